// Round 15
// baseline (550.205 us; speedup 1.0000x reference)
//
#include <hip/hip_runtime.h>
#include <hip/hip_bf16.h>

constexpr int N_USER = 100000;
constexpr int N_ITEM = 200000;
constexpr int N_ALL  = N_USER + N_ITEM;
constexpr int E_UI   = 3200000;
constexpr int E_UU   = 1600000;
constexpr int D      = 64;
constexpr int BLK    = 256;

// bucketing: 2048 rows per bucket
constexpr int RPB_SHIFT = 11;
constexpr int RPB       = 1 << RPB_SHIFT;   // 2048
constexpr int MAX_NB    = 160;
constexpr int SRC_BITS  = 19;               // N_ALL < 2^19
constexpr int SRC_MASK  = (1 << SRC_BITS) - 1;

// bin_scatter tile geometry
constexpr int SBLK = 512;
constexpr int EPT  = 16;
constexpr int TILE = SBLK * EPT;            // 8192 edges per block

constexpr int FBLK  = 1024;                 // finalize block (16 waves)
constexpr int NBINS = 64;                   // degree-sort bins (clamp)

constexpr int NB_UI = (N_ALL  + RPB - 1) / RPB;  // 147
constexpr int NB_UU = (N_USER + RPB - 1) / RPB;  // 49
constexpr int T_UI  = (E_UI + TILE - 1) / TILE;  // 391
constexpr int T_UU  = (E_UU + TILE - 1) / TILE;  // 196
constexpr int H_UI  = 384;
constexpr int H_UU  = 128;

typedef __hip_bfloat16 bf16;
typedef float f32x4 __attribute__((ext_vector_type(4)));
typedef int   i32x4 __attribute__((ext_vector_type(4)));

// ---------------- small helpers ----------------

__device__ inline int wave_incl_scan(int x, int lane) {
    #pragma unroll
    for (int off = 1; off < 64; off <<= 1) {
        int y = __shfl_up(x, off, 64);
        if (lane >= off) x += y;
    }
    return x;
}

static inline int cdiv(int a, int b) { return (a + b - 1) / b; }

// accumulate 8 bf16 (packed in an int4) into 8 f32 accumulators
__device__ inline void acc8(float* acc, const int4 v) {
    acc[0] += __int_as_float(v.x << 16);
    acc[1] += __int_as_float(v.x & 0xffff0000);
    acc[2] += __int_as_float(v.y << 16);
    acc[3] += __int_as_float(v.y & 0xffff0000);
    acc[4] += __int_as_float(v.z << 16);
    acc[5] += __int_as_float(v.z & 0xffff0000);
    acc[6] += __int_as_float(v.w << 16);
    acc[7] += __int_as_float(v.w & 0xffff0000);
}

__device__ inline void unpack8(const i32x4 v, float* f) {
    f[0] = __int_as_float(v.x << 16);
    f[1] = __int_as_float(v.x & 0xffff0000);
    f[2] = __int_as_float(v.y << 16);
    f[3] = __int_as_float(v.y & 0xffff0000);
    f[4] = __int_as_float(v.z << 16);
    f[5] = __int_as_float(v.z & 0xffff0000);
    f[6] = __int_as_float(v.w << 16);
    f[7] = __int_as_float(v.w & 0xffff0000);
}

// L2-norm inverse across the 8 lanes of one row slot
__device__ inline float groupnorm_inv(const float* f) {
    float ss = 0.f;
    #pragma unroll
    for (int k = 0; k < 8; ++k) ss += f[k] * f[k];
    ss += __shfl_xor(ss, 1, 64);
    ss += __shfl_xor(ss, 2, 64);
    ss += __shfl_xor(ss, 4, 64);
    return 1.0f / fmaxf(sqrtf(ss), 1e-12f);
}

// ---------------- init kernels ----------------

__global__ void init_ui_kernel(const float* __restrict__ ue,
                               const float* __restrict__ ie,
                               const float* __restrict__ rsq_out,
                               bf16* __restrict__ emb_scaled) {
    size_t t = (size_t)blockIdx.x * blockDim.x + threadIdx.x;
    const size_t total = (size_t)N_ALL * D;
    if (t >= total) return;
    const size_t userN = (size_t)N_USER * D;
    float v = (t < userN) ? ue[t] : ie[t - userN];
    int row = (int)(t >> 6);
    emb_scaled[t] = __float2bfloat16(v * rsq_out[row]);
}

__global__ void init_uu_kernel(const float* __restrict__ ue,
                               const float* __restrict__ rsq_out,
                               bf16* __restrict__ emb_scaled) {
    size_t t = (size_t)blockIdx.x * blockDim.x + threadIdx.x;
    const size_t total = (size_t)N_USER * D;
    if (t >= total) return;
    float v = ue[t];
    int row = (int)(t >> 6);
    emb_scaled[t] = __float2bfloat16(v * rsq_out[row]);
}

// ---------------- merged bucket histogram: both graphs, both sides ----------------
// bc layout: [UI_D | UI_S | UU_D | UU_S], each MAX_NB ints.

__global__ void bucket_hist_both_kernel(const int* __restrict__ ui_src,
                                        const int* __restrict__ ui_dst,
                                        const int* __restrict__ uu_src,
                                        const int* __restrict__ uu_dst,
                                        int* __restrict__ bc) {
    __shared__ int cD[MAX_NB];
    __shared__ int cS[MAX_NB];
    bool isUI = blockIdx.x < H_UI;
    const int* src = isUI ? ui_src : uu_src;
    const int* dst = isUI ? ui_dst : uu_dst;
    int E  = isUI ? E_UI : E_UU;
    int nb = isUI ? NB_UI : NB_UU;
    int* gD = bc + (isUI ? 0 : 2 * MAX_NB);
    int* gS = gD + MAX_NB;
    int bi  = isUI ? blockIdx.x : blockIdx.x - H_UI;
    int nbk = isUI ? H_UI : H_UU;
    for (int b = threadIdx.x; b < nb; b += BLK) { cD[b] = 0; cS[b] = 0; }
    __syncthreads();
    for (int e = bi * BLK + threadIdx.x; e < E; e += nbk * BLK) {
        atomicAdd(&cD[dst[e] >> RPB_SHIFT], 1);
        atomicAdd(&cS[src[e] >> RPB_SHIFT], 1);
    }
    __syncthreads();
    for (int b = threadIdx.x; b < nb; b += BLK) {
        if (cD[b]) atomicAdd(&gD[b], cD[b]);
        if (cS[b]) atomicAdd(&gS[b], cS[b]);
    }
}

// ---------------- single-block exclusive scans (all 4 arrays) ----------------

__device__ void scan_one(const int* __restrict__ cnt, int nb,
                         int* __restrict__ base, int* __restrict__ cursor,
                         int* wsum, int* carry_s) {
    int t = threadIdx.x, lane = t & 63, wid = t >> 6;
    if (t == 0) *carry_s = 0;
    for (int b0 = 0; b0 < nb; b0 += BLK) {
        __syncthreads();
        int i = b0 + t;
        int x = (i < nb) ? cnt[i] : 0;
        int s = wave_incl_scan(x, lane);
        if (lane == 63) wsum[wid] = s;
        __syncthreads();
        int add = *carry_s;
        for (int w = 0; w < wid; ++w) add += wsum[w];
        int excl = add + s - x;
        if (i < nb) { base[i] = excl; cursor[i] = excl; }
        int total = wsum[0] + wsum[1] + wsum[2] + wsum[3];
        __syncthreads();
        if (t == 0) *carry_s = add + total;  // add == old carry for t0
    }
    __syncthreads();
    if (t == 0) base[nb] = *carry_s;
    __syncthreads();
}

// bases: 4 arrays of (MAX_NB+1); curs: 4 arrays of MAX_NB (same order as bc)
__global__ void scan4_kernel(const int* __restrict__ bc,
                             int* __restrict__ bases,
                             int* __restrict__ curs) {
    __shared__ int wsum[4];
    __shared__ int carry_s;
    scan_one(bc + 0 * MAX_NB, NB_UI, bases + 0 * (MAX_NB + 1), curs + 0 * MAX_NB, wsum, &carry_s);
    scan_one(bc + 1 * MAX_NB, NB_UI, bases + 1 * (MAX_NB + 1), curs + 1 * MAX_NB, wsum, &carry_s);
    scan_one(bc + 2 * MAX_NB, NB_UU, bases + 2 * (MAX_NB + 1), curs + 2 * MAX_NB, wsum, &carry_s);
    scan_one(bc + 3 * MAX_NB, NB_UU, bases + 3 * (MAX_NB + 1), curs + 3 * MAX_NB, wsum, &carry_s);
}

// ---------------- merged bin scatter: both graphs, both sides, one edge pass ----------------
// dst record packed as (dstLocal << SRC_BITS) | src.

__global__ __launch_bounds__(SBLK) void bin_scatter2_both_kernel(
    const int* __restrict__ ui_src, const int* __restrict__ ui_dst,
    const int* __restrict__ uu_src, const int* __restrict__ uu_dst,
    int* __restrict__ curs,
    int* __restrict__ ui_binned_src, int* __restrict__ ui_binned,
    int* __restrict__ uu_binned_src, int* __restrict__ uu_binned) {
    __shared__ int cS[MAX_NB];
    __shared__ int bS[MAX_NB];
    __shared__ int cD[MAX_NB];
    __shared__ int bD[MAX_NB];
    bool isUI = blockIdx.x < T_UI;
    const int* src = isUI ? ui_src : uu_src;
    const int* dst = isUI ? ui_dst : uu_dst;
    int E  = isUI ? E_UI : E_UU;
    int nb = isUI ? NB_UI : NB_UU;
    int* curD = curs + (isUI ? 0 : 2 * MAX_NB);
    int* curS = curD + MAX_NB;
    int* bsrc = isUI ? ui_binned_src : uu_binned_src;
    int* bpk  = isUI ? ui_binned : uu_binned;
    int ti = isUI ? blockIdx.x : blockIdx.x - T_UI;

    int t = threadIdx.x;
    for (int b = t; b < nb; b += SBLK) { cS[b] = 0; cD[b] = 0; }
    __syncthreads();
    int base_e = ti * TILE;
    int mys[EPT], myd[EPT], myrS[EPT], myrD[EPT];
    #pragma unroll
    for (int j = 0; j < EPT; ++j) {
        int e = base_e + j * SBLK + t;
        if (e < E) {
            int s = src[e];
            int d = dst[e];
            mys[j] = s;
            myd[j] = d;
            myrS[j] = atomicAdd(&cS[s >> RPB_SHIFT], 1);
            myrD[j] = atomicAdd(&cD[d >> RPB_SHIFT], 1);
        } else {
            myd[j] = -1;
        }
    }
    __syncthreads();
    for (int b = t; b < nb; b += SBLK) {
        if (cS[b] > 0) bS[b] = atomicAdd(&curS[b], cS[b]);
        if (cD[b] > 0) bD[b] = atomicAdd(&curD[b], cD[b]);
    }
    __syncthreads();
    #pragma unroll
    for (int j = 0; j < EPT; ++j) {
        if (myd[j] >= 0) {
            int s = mys[j], d = myd[j];
            bsrc[bS[s >> RPB_SHIFT] + myrS[j]] = s;
            bpk[bD[d >> RPB_SHIFT] + myrD[j]] = ((d & (RPB - 1)) << SRC_BITS) | s;
        }
    }
}

// ---------------- merged per-bucket finalize + within-bucket degree sort ----------------
// blocks: [0,NB_UI) UI-dst, [NB_UI,2*NB_UI) UI-src,
//         [2*NB_UI, 2*NB_UI+NB_UU) UU-dst, rest UU-src.
// dst-side additionally emits perm[row0+rank] = row (descending degree within bucket).

__global__ __launch_bounds__(FBLK) void bucket_finalize_both_kernel(
    const int* __restrict__ ui_binned, const int* __restrict__ ui_binned_src,
    const int* __restrict__ uu_binned, const int* __restrict__ uu_binned_src,
    const int* __restrict__ bases,
    int* __restrict__ ui_row_ptr, float* __restrict__ ui_rsq_in,
    int* __restrict__ ui_col, float* __restrict__ ui_rsq_out,
    int* __restrict__ ui_perm,
    int* __restrict__ uu_row_ptr, float* __restrict__ uu_rsq_in,
    int* __restrict__ uu_col, float* __restrict__ uu_rsq_out,
    int* __restrict__ uu_perm) {
    __shared__ int deg[RPB];
    __shared__ int cur[RPB];
    __shared__ int wsum[FBLK / 64];
    __shared__ int carry;
    __shared__ int hist[NBINS];
    __shared__ int hbase[NBINS];
    int bb = blockIdx.x;
    int t = threadIdx.x, lane = t & 63, wid = t >> 6;

    const int* binned = nullptr;
    const int* base = nullptr;
    int* row_ptr = nullptr;
    float* rsq_in = nullptr;
    int* col = nullptr;
    float* rsq_out = nullptr;
    int* perm = nullptr;
    int b = 0, nb = 0, n = 0;
    bool dstSide;
    if (bb < NB_UI) {
        dstSide = true; b = bb; nb = NB_UI; n = N_ALL;
        binned = ui_binned; base = bases;
        row_ptr = ui_row_ptr; rsq_in = ui_rsq_in; col = ui_col; perm = ui_perm;
    } else if (bb < 2 * NB_UI) {
        dstSide = false; b = bb - NB_UI; nb = NB_UI; n = N_ALL;
        binned = ui_binned_src; base = bases + (MAX_NB + 1);
        rsq_out = ui_rsq_out;
    } else if (bb < 2 * NB_UI + NB_UU) {
        dstSide = true; b = bb - 2 * NB_UI; nb = NB_UU; n = N_USER;
        binned = uu_binned; base = bases + 2 * (MAX_NB + 1);
        row_ptr = uu_row_ptr; rsq_in = uu_rsq_in; col = uu_col; perm = uu_perm;
    } else {
        dstSide = false; b = bb - 2 * NB_UI - NB_UU; nb = NB_UU; n = N_USER;
        binned = uu_binned_src; base = bases + 3 * (MAX_NB + 1);
        rsq_out = uu_rsq_out;
    }

    int row0 = b << RPB_SHIFT;
    int beg = base[b], end = base[b + 1];

    if (!dstSide) {
        for (int i = t; i < RPB; i += FBLK) deg[i] = 0;
        __syncthreads();
        for (int e = beg + t; e < end; e += FBLK)
            atomicAdd(&deg[binned[e] - row0], 1);
        __syncthreads();
        for (int i = t; i < RPB; i += FBLK)
            if (row0 + i < n)
                rsq_out[row0 + i] = 1.0f / sqrtf(fmaxf((float)deg[i], 1.0f));
        return;
    }

    int nrows = min(RPB, n - row0);
    for (int i = t; i < RPB; i += FBLK) deg[i] = 0;
    for (int i = t; i < NBINS; i += FBLK) hist[i] = 0;
    __syncthreads();

    for (int e = beg + t; e < end; e += FBLK)
        atomicAdd(&deg[binned[e] >> SRC_BITS], 1);

    if (t == 0) carry = 0;
    for (int c0 = 0; c0 < RPB; c0 += FBLK) {
        __syncthreads();
        int x = deg[c0 + t];
        int s = wave_incl_scan(x, lane);
        if (lane == 63) wsum[wid] = s;
        __syncthreads();
        int add = carry;
        for (int w = 0; w < wid; ++w) add += wsum[w];
        int excl = add + s - x;
        cur[c0 + t] = beg + excl;
        if (c0 + t < nrows) {
            row_ptr[row0 + c0 + t] = beg + excl;
            rsq_in[row0 + c0 + t] = 1.0f / sqrtf(fmaxf((float)x, 1.0f));
        }
        int total = 0;
        #pragma unroll
        for (int w = 0; w < FBLK / 64; ++w) total += wsum[w];
        __syncthreads();
        if (t == 0) carry = add + total;
    }
    __syncthreads();
    if (b == nb - 1 && t == 0) row_ptr[n] = end;
    __syncthreads();

    // col scatter (mutates cur; deg untouched)
    for (int e = beg + t; e < end; e += FBLK) {
        int p = binned[e];
        int pos = atomicAdd(&cur[p >> SRC_BITS], 1);
        col[pos] = p & SRC_MASK;
    }
    __syncthreads();

    // within-bucket descending-degree counting sort -> perm
    for (int i = t; i < nrows; i += FBLK) {
        int key = (NBINS - 1) - min(deg[i], NBINS - 1);
        atomicAdd(&hist[key], 1);
    }
    __syncthreads();
    if (t < NBINS) {
        int x = hist[t];
        int s = wave_incl_scan(x, t);   // t < 64 -> wave 0, lane == t
        hbase[t] = s - x;
    }
    __syncthreads();
    for (int i = t; i < nrows; i += FBLK) {
        int key = (NBINS - 1) - min(deg[i], NBINS - 1);
        int r = atomicAdd(&hbase[key], 1);
        perm[row0 + r] = row0 + i;
    }
}

// ---------------- plain GCN layer: gather -> emb_out only (degree-sorted) ----------------

__global__ void gcn_layer_plain_kernel(const int* __restrict__ perm,
                                       const int* __restrict__ row_ptr,
                                       const int* __restrict__ col,
                                       const bf16* __restrict__ emb_in,
                                       const float* __restrict__ rsq_in,
                                       const float* __restrict__ rsq_out,
                                       bf16* __restrict__ emb_out,
                                       int n) {
    int wave = blockIdx.x * (blockDim.x >> 6) + (threadIdx.x >> 6);
    int lane = threadIdx.x & 63;
    int q = lane & 7;
    int idx = wave * 8 + (lane >> 3);
    bool act = idx < n;
    int row = act ? perm[idx] : 0;
    int beg = 0, end = 0;
    if (act) { beg = row_ptr[row]; end = row_ptr[row + 1]; }
    float rin = act ? rsq_in[row] : 0.f;
    float ro  = act ? rsq_out[row] : 0.f;

    float acc[8];
    #pragma unroll
    for (int k = 0; k < 8; ++k) acc[k] = 0.f;

    const int4* __restrict__ embv = (const int4*)emb_in;

    int e = beg;
    for (; e + 4 <= end; e += 4) {
        int s0 = col[e];
        int s1 = col[e + 1];
        int s2 = col[e + 2];
        int s3 = col[e + 3];
        int4 w0 = embv[(size_t)s0 * 8 + q];
        int4 w1 = embv[(size_t)s1 * 8 + q];
        int4 w2 = embv[(size_t)s2 * 8 + q];
        int4 w3 = embv[(size_t)s3 * 8 + q];
        acc8(acc, w0);
        acc8(acc, w1);
        acc8(acc, w2);
        acc8(acc, w3);
    }
    for (; e < end; ++e) {
        int4 w0 = embv[(size_t)col[e] * 8 + q];
        acc8(acc, w0);
    }

    float vv[8];
    #pragma unroll
    for (int k = 0; k < 8; ++k) {
        float v = acc[k] * rin;
        vv[k] = (v > 0.f) ? v : 0.5f * v;   // LeakyReLU(0.5)
    }

    if (act) {
        size_t o = (size_t)row * D + (size_t)q * 8;
        union { i32x4 i4; bf16 h[8]; } pk;
        #pragma unroll
        for (int k = 0; k < 8; ++k) pk.h[k] = __float2bfloat16(vv[k] * ro);
        __builtin_nontemporal_store(pk.i4, (i32x4*)(emb_out + o));
    }
}

// ---------------- final GCN layer: own contribution + recomputed prior norms ----------------
// sum_out[row] = init[row] + n(prev1[row]) [+ n(prev2[row])] + v/||v||

__global__ void gcn_layer_final_kernel(const int* __restrict__ perm,
                                       const int* __restrict__ row_ptr,
                                       const int* __restrict__ col,
                                       const bf16* __restrict__ emb_in,
                                       const float* __restrict__ rsq_in,
                                       const float* __restrict__ initA,
                                       const float* __restrict__ initB,
                                       long splitElems,
                                       const bf16* __restrict__ prev1,
                                       const bf16* __restrict__ prev2,
                                       float* __restrict__ sum_out,
                                       int n) {
    int wave = blockIdx.x * (blockDim.x >> 6) + (threadIdx.x >> 6);
    int lane = threadIdx.x & 63;
    int q = lane & 7;
    int idx = wave * 8 + (lane >> 3);
    bool act = idx < n;
    int row = act ? perm[idx] : 0;
    int beg = 0, end = 0;
    if (act) { beg = row_ptr[row]; end = row_ptr[row + 1]; }
    float rin = act ? rsq_in[row] : 0.f;
    size_t o = (size_t)row * D + (size_t)q * 8;

    // hoisted: init base (nt, streamed once)
    f32x4 i0 = {0.f, 0.f, 0.f, 0.f}, i1 = {0.f, 0.f, 0.f, 0.f};
    if (act) {
        const float* bsrc = ((size_t)row * D < (size_t)splitElems)
                                ? (initA + o) : (initB + (o - splitElems));
        const f32x4* sp = (const f32x4*)bsrc;
        i0 = __builtin_nontemporal_load(sp);
        i1 = __builtin_nontemporal_load(sp + 1);
    }
    // hoisted: prior emb rows
    float p1f[8], p2f[8];
    #pragma unroll
    for (int k = 0; k < 8; ++k) { p1f[k] = 0.f; p2f[k] = 0.f; }
    if (act) {
        size_t idx2 = (size_t)row * 8 + q;
        i32x4 p1;
        if (prev1 == emb_in) p1 = *((const i32x4*)prev1 + idx2);   // gather table: keep cached
        else p1 = __builtin_nontemporal_load((const i32x4*)prev1 + idx2);
        unpack8(p1, p1f);
        if (prev2) {
            i32x4 p2 = *((const i32x4*)prev2 + idx2);
            unpack8(p2, p2f);
        }
    }

    float acc[8];
    #pragma unroll
    for (int k = 0; k < 8; ++k) acc[k] = 0.f;

    const int4* __restrict__ embv = (const int4*)emb_in;

    int e = beg;
    for (; e + 4 <= end; e += 4) {
        int s0 = col[e];
        int s1 = col[e + 1];
        int s2 = col[e + 2];
        int s3 = col[e + 3];
        int4 w0 = embv[(size_t)s0 * 8 + q];
        int4 w1 = embv[(size_t)s1 * 8 + q];
        int4 w2 = embv[(size_t)s2 * 8 + q];
        int4 w3 = embv[(size_t)s3 * 8 + q];
        acc8(acc, w0);
        acc8(acc, w1);
        acc8(acc, w2);
        acc8(acc, w3);
    }
    for (; e < end; ++e) {
        int4 w0 = embv[(size_t)col[e] * 8 + q];
        acc8(acc, w0);
    }

    float vv[8];
    #pragma unroll
    for (int k = 0; k < 8; ++k) {
        float v = acc[k] * rin;
        vv[k] = (v > 0.f) ? v : 0.5f * v;   // LeakyReLU(0.5)
    }
    float invO = groupnorm_inv(vv);
    float inv1 = groupnorm_inv(p1f);
    float inv2 = prev2 ? groupnorm_inv(p2f) : 0.f;

    if (act) {
        f32x4 o0, o1;
        o0.x = i0.x + p1f[0] * inv1 + p2f[0] * inv2 + vv[0] * invO;
        o0.y = i0.y + p1f[1] * inv1 + p2f[1] * inv2 + vv[1] * invO;
        o0.z = i0.z + p1f[2] * inv1 + p2f[2] * inv2 + vv[2] * invO;
        o0.w = i0.w + p1f[3] * inv1 + p2f[3] * inv2 + vv[3] * invO;
        o1.x = i1.x + p1f[4] * inv1 + p2f[4] * inv2 + vv[4] * invO;
        o1.y = i1.y + p1f[5] * inv1 + p2f[5] * inv2 + vv[5] * invO;
        o1.z = i1.z + p1f[6] * inv1 + p2f[6] * inv2 + vv[6] * invO;
        o1.w = i1.w + p1f[7] * inv1 + p2f[7] * inv2 + vv[7] * invO;
        f32x4* op = (f32x4*)(sum_out + o);
        __builtin_nontemporal_store(o0, op);
        __builtin_nontemporal_store(o1, op + 1);
    }
}

// ---------------- host side ----------------

extern "C" void kernel_launch(void* const* d_in, const int* in_sizes, int n_in,
                              void* d_out, int out_size, void* d_ws, size_t ws_size,
                              hipStream_t stream) {
    const float* user_emb = (const float*)d_in[0];
    const float* item_emb = (const float*)d_in[1];
    const int*   ui_src   = (const int*)d_in[2];
    const int*   ui_dst   = (const int*)d_in[3];
    const int*   uu_src   = (const int*)d_in[4];
    const int*   uu_dst   = (const int*)d_in[5];

    float* out    = (float*)d_out;
    float* ui_sum = out;                          // [N_ALL * D]
    float* uu_sum = out + (size_t)N_ALL * D;      // [N_USER * D]

    // ws layout
    char* wp = (char*)d_ws;
    bf16* embA = (bf16*)wp;        wp += (size_t)N_ALL * D * sizeof(bf16);   // 38.4 MB
    bf16* embB = (bf16*)wp;        wp += (size_t)N_ALL * D * sizeof(bf16);   // 38.4 MB
    int* ui_binned     = (int*)wp; wp += (size_t)E_UI * sizeof(int);         // 12.8 MB
    int* ui_binned_src = (int*)wp; wp += (size_t)E_UI * sizeof(int);         // 12.8 MB
    int* uu_binned     = (int*)wp; wp += (size_t)E_UU * sizeof(int);         // 6.4 MB
    int* uu_binned_src = (int*)wp; wp += (size_t)E_UU * sizeof(int);         // 6.4 MB
    int*   uu_col     = (int*)wp;   wp += (size_t)E_UU * sizeof(int);        // 6.4 MB
    int*   uu_row_ptr = (int*)wp;   wp += (size_t)(N_USER + 1) * sizeof(int);
    float* uu_rsq_out = (float*)wp; wp += (size_t)N_USER * sizeof(float);
    float* uu_rsq_in  = (float*)wp; wp += (size_t)N_USER * sizeof(float);
    int*   uu_perm    = (int*)wp;   wp += (size_t)N_USER * sizeof(int);
    int* bc    = (int*)wp; wp += 4 * (size_t)MAX_NB * sizeof(int);
    int* bases = (int*)wp; wp += 4 * (size_t)(MAX_NB + 1) * sizeof(int);
    int* curs  = (int*)wp; wp += 4 * (size_t)MAX_NB * sizeof(int);

    // UI CSR scratch in the uu_sum region of d_out (dead during UI phase)
    char* p = (char*)uu_sum;
    int*   ui_col     = (int*)p;   p += (size_t)E_UI * sizeof(int);
    int*   ui_row_ptr = (int*)p;   p += (size_t)(N_ALL + 1) * sizeof(int);
    float* ui_rsq_out = (float*)p; p += (size_t)N_ALL * sizeof(float);
    float* ui_rsq_in  = (float*)p; p += (size_t)N_ALL * sizeof(float);
    int*   ui_perm    = (int*)p;   p += (size_t)N_ALL * sizeof(int);

    // ---------------- merged build (both graphs) ----------------
    (void)hipMemsetAsync(bc, 0, 4 * (size_t)MAX_NB * sizeof(int), stream);
    bucket_hist_both_kernel<<<H_UI + H_UU, BLK, 0, stream>>>(
        ui_src, ui_dst, uu_src, uu_dst, bc);
    scan4_kernel<<<1, BLK, 0, stream>>>(bc, bases, curs);
    bin_scatter2_both_kernel<<<T_UI + T_UU, SBLK, 0, stream>>>(
        ui_src, ui_dst, uu_src, uu_dst, curs,
        ui_binned_src, ui_binned, uu_binned_src, uu_binned);
    bucket_finalize_both_kernel<<<2 * NB_UI + 2 * NB_UU, FBLK, 0, stream>>>(
        ui_binned, ui_binned_src, uu_binned, uu_binned_src, bases,
        ui_row_ptr, ui_rsq_in, ui_col, ui_rsq_out, ui_perm,
        uu_row_ptr, uu_rsq_in, uu_col, uu_rsq_out, uu_perm);

    const int ROWS_PER_BLK = (BLK / 64) * 8;  // 32

    // ---------------- user-item graph ----------------
    {
        size_t tot = (size_t)N_ALL * D;
        init_ui_kernel<<<cdiv((int)tot, BLK), BLK, 0, stream>>>(
            user_emb, item_emb, ui_rsq_out, embA);

        int grid = cdiv(N_ALL, ROWS_PER_BLK);
        // l0: A -> B (emb_1)
        gcn_layer_plain_kernel<<<grid, BLK, 0, stream>>>(
            ui_perm, ui_row_ptr, ui_col, embA, ui_rsq_in, ui_rsq_out, embB, N_ALL);
        // l1: B -> A (emb_2)
        gcn_layer_plain_kernel<<<grid, BLK, 0, stream>>>(
            ui_perm, ui_row_ptr, ui_col, embB, ui_rsq_in, ui_rsq_out, embA, N_ALL);
        // l2: gather A, combine init + n(emb_1=B) + n(emb_2=A) + own -> ui_sum
        gcn_layer_final_kernel<<<grid, BLK, 0, stream>>>(
            ui_perm, ui_row_ptr, ui_col, embA, ui_rsq_in,
            user_emb, item_emb, (long)N_USER * D,
            embB, embA, ui_sum, N_ALL);
    }

    // ---------------- user-user graph ----------------
    {
        size_t tot = (size_t)N_USER * D;
        init_uu_kernel<<<cdiv((int)tot, BLK), BLK, 0, stream>>>(
            user_emb, uu_rsq_out, embA);

        int grid = cdiv(N_USER, ROWS_PER_BLK);
        // l0: A -> B (emb_1)
        gcn_layer_plain_kernel<<<grid, BLK, 0, stream>>>(
            uu_perm, uu_row_ptr, uu_col, embA, uu_rsq_in, uu_rsq_out, embB, N_USER);
        // l1: gather B, combine init(ue) + n(emb_1=B) + own -> uu_sum
        gcn_layer_final_kernel<<<grid, BLK, 0, stream>>>(
            uu_perm, uu_row_ptr, uu_col, embB, uu_rsq_in,
            user_emb, nullptr, (long)N_USER * D,
            embB, nullptr, uu_sum, N_USER);
    }
}

// Round 16
// 466.164 us; speedup vs baseline: 1.1803x; 1.1803x over previous
//
#include <hip/hip_runtime.h>
#include <hip/hip_bf16.h>

constexpr int N_USER = 100000;
constexpr int N_ITEM = 200000;
constexpr int N_ALL  = N_USER + N_ITEM;
constexpr int E_UI   = 3200000;
constexpr int E_UU   = 1600000;
constexpr int D      = 64;
constexpr int BLK    = 256;

// bucketing: 2048 rows per bucket
constexpr int RPB_SHIFT = 11;
constexpr int RPB       = 1 << RPB_SHIFT;   // 2048
constexpr int MAX_NB    = 160;
constexpr int SRC_BITS  = 19;               // N_ALL < 2^19
constexpr int SRC_MASK  = (1 << SRC_BITS) - 1;

// fixed per-bucket capacity (mean + >35 sigma for uniform-random endpoints)
constexpr int NB_UI = (N_ALL  + RPB - 1) / RPB;  // 147
constexpr int NB_UU = (N_USER + RPB - 1) / RPB;  // 49
constexpr int CAP_UI = 27392;               // mean 21845, sigma ~147
constexpr int CAP_UU = 40960;               // mean 32768, sigma ~179

// bin_scatter tile geometry
constexpr int SBLK = 512;
constexpr int EPT  = 16;
constexpr int TILE = SBLK * EPT;            // 8192 edges per block

constexpr int FBLK = 1024;                  // finalize block (16 waves)

constexpr int T_UI  = (E_UI + TILE - 1) / TILE;  // 391
constexpr int T_UU  = (E_UU + TILE - 1) / TILE;  // 196

typedef __hip_bfloat16 bf16;
typedef float f32x4 __attribute__((ext_vector_type(4)));
typedef int   i32x4 __attribute__((ext_vector_type(4)));

// ---------------- small helpers ----------------

__device__ inline int wave_incl_scan(int x, int lane) {
    #pragma unroll
    for (int off = 1; off < 64; off <<= 1) {
        int y = __shfl_up(x, off, 64);
        if (lane >= off) x += y;
    }
    return x;
}

static inline int cdiv(int a, int b) { return (a + b - 1) / b; }

// accumulate 8 bf16 (packed in an int4) into 8 f32 accumulators
__device__ inline void acc8(float* acc, const int4 v) {
    acc[0] += __int_as_float(v.x << 16);
    acc[1] += __int_as_float(v.x & 0xffff0000);
    acc[2] += __int_as_float(v.y << 16);
    acc[3] += __int_as_float(v.y & 0xffff0000);
    acc[4] += __int_as_float(v.z << 16);
    acc[5] += __int_as_float(v.z & 0xffff0000);
    acc[6] += __int_as_float(v.w << 16);
    acc[7] += __int_as_float(v.w & 0xffff0000);
}

__device__ inline void unpack8(const i32x4 v, float* f) {
    f[0] = __int_as_float(v.x << 16);
    f[1] = __int_as_float(v.x & 0xffff0000);
    f[2] = __int_as_float(v.y << 16);
    f[3] = __int_as_float(v.y & 0xffff0000);
    f[4] = __int_as_float(v.z << 16);
    f[5] = __int_as_float(v.z & 0xffff0000);
    f[6] = __int_as_float(v.w << 16);
    f[7] = __int_as_float(v.w & 0xffff0000);
}

// L2-norm inverse across the 8 lanes of one row slot
__device__ inline float groupnorm_inv(const float* f) {
    float ss = 0.f;
    #pragma unroll
    for (int k = 0; k < 8; ++k) ss += f[k] * f[k];
    ss += __shfl_xor(ss, 1, 64);
    ss += __shfl_xor(ss, 2, 64);
    ss += __shfl_xor(ss, 4, 64);
    return 1.0f / fmaxf(sqrtf(ss), 1e-12f);
}

// ---------------- init kernels ----------------

__global__ void init_ui_kernel(const float* __restrict__ ue,
                               const float* __restrict__ ie,
                               const float* __restrict__ rsq_out,
                               bf16* __restrict__ emb_scaled) {
    size_t t = (size_t)blockIdx.x * blockDim.x + threadIdx.x;
    const size_t total = (size_t)N_ALL * D;
    if (t >= total) return;
    const size_t userN = (size_t)N_USER * D;
    float v = (t < userN) ? ue[t] : ie[t - userN];
    int row = (int)(t >> 6);
    emb_scaled[t] = __float2bfloat16(v * rsq_out[row]);
}

__global__ void init_uu_kernel(const float* __restrict__ ue,
                               const float* __restrict__ rsq_out,
                               bf16* __restrict__ emb_scaled) {
    size_t t = (size_t)blockIdx.x * blockDim.x + threadIdx.x;
    const size_t total = (size_t)N_USER * D;
    if (t >= total) return;
    float v = ue[t];
    int row = (int)(t >> 6);
    emb_scaled[t] = __float2bfloat16(v * rsq_out[row]);
}

// ---------------- cursor init: curX[b] = b * CAP ----------------
// layout: [UI_D | UI_S | UU_D | UU_S], each MAX_NB ints.

__global__ void init_cursors_kernel(int* __restrict__ curs) {
    int t = threadIdx.x;
    if (t < NB_UI) {
        curs[0 * MAX_NB + t] = t * CAP_UI;
        curs[1 * MAX_NB + t] = t * CAP_UI;
    }
    if (t < NB_UU) {
        curs[2 * MAX_NB + t] = t * CAP_UU;
        curs[3 * MAX_NB + t] = t * CAP_UU;
    }
}

// ---------------- merged bin scatter: both graphs, both sides, one edge pass ----------------
// dst record packed as (dstLocal << SRC_BITS) | src. Output bucket-strided at CAP.

__global__ __launch_bounds__(SBLK) void bin_scatter2_both_kernel(
    const int* __restrict__ ui_src, const int* __restrict__ ui_dst,
    const int* __restrict__ uu_src, const int* __restrict__ uu_dst,
    int* __restrict__ curs,
    int* __restrict__ ui_binned_src, int* __restrict__ ui_binned,
    int* __restrict__ uu_binned_src, int* __restrict__ uu_binned) {
    __shared__ int cS[MAX_NB];
    __shared__ int bS[MAX_NB];
    __shared__ int cD[MAX_NB];
    __shared__ int bD[MAX_NB];
    bool isUI = blockIdx.x < T_UI;
    const int* src = isUI ? ui_src : uu_src;
    const int* dst = isUI ? ui_dst : uu_dst;
    int E  = isUI ? E_UI : E_UU;
    int nb = isUI ? NB_UI : NB_UU;
    int* curD = curs + (isUI ? 0 : 2 * MAX_NB);
    int* curS = curD + MAX_NB;
    int* bsrc = isUI ? ui_binned_src : uu_binned_src;
    int* bpk  = isUI ? ui_binned : uu_binned;
    int ti = isUI ? blockIdx.x : blockIdx.x - T_UI;

    int t = threadIdx.x;
    for (int b = t; b < nb; b += SBLK) { cS[b] = 0; cD[b] = 0; }
    __syncthreads();
    int base_e = ti * TILE;
    int mys[EPT], myd[EPT], myrS[EPT], myrD[EPT];
    #pragma unroll
    for (int j = 0; j < EPT; ++j) {
        int e = base_e + j * SBLK + t;
        if (e < E) {
            int s = src[e];
            int d = dst[e];
            mys[j] = s;
            myd[j] = d;
            myrS[j] = atomicAdd(&cS[s >> RPB_SHIFT], 1);
            myrD[j] = atomicAdd(&cD[d >> RPB_SHIFT], 1);
        } else {
            myd[j] = -1;
        }
    }
    __syncthreads();
    for (int b = t; b < nb; b += SBLK) {
        if (cS[b] > 0) bS[b] = atomicAdd(&curS[b], cS[b]);
        if (cD[b] > 0) bD[b] = atomicAdd(&curD[b], cD[b]);
    }
    __syncthreads();
    #pragma unroll
    for (int j = 0; j < EPT; ++j) {
        if (myd[j] >= 0) {
            int s = mys[j], d = myd[j];
            bsrc[bS[s >> RPB_SHIFT] + myrS[j]] = s;
            bpk[bD[d >> RPB_SHIFT] + myrD[j]] = ((d & (RPB - 1)) << SRC_BITS) | s;
        }
    }
}

// ---------------- merged per-bucket finalize ----------------
// blocks: [0,NB_UI) UI-dst, [NB_UI,2*NB_UI) UI-src,
//         [2*NB_UI, 2*NB_UI+NB_UU) UU-dst, rest UU-src.
// dst-side: deg count -> row_beg/row_end/rsq_in, col scatter (bucket-strided).
// src-side: out-degree -> rsq_out.
// Bucket edge range: beg = b*CAP, end = cursor final value.

__global__ __launch_bounds__(FBLK) void bucket_finalize_both_kernel(
    const int* __restrict__ ui_binned, const int* __restrict__ ui_binned_src,
    const int* __restrict__ uu_binned, const int* __restrict__ uu_binned_src,
    const int* __restrict__ curs,
    int* __restrict__ ui_row_beg, int* __restrict__ ui_row_end,
    float* __restrict__ ui_rsq_in,
    int* __restrict__ ui_col, float* __restrict__ ui_rsq_out,
    int* __restrict__ uu_row_beg, int* __restrict__ uu_row_end,
    float* __restrict__ uu_rsq_in,
    int* __restrict__ uu_col, float* __restrict__ uu_rsq_out) {
    __shared__ int deg[RPB];
    __shared__ int cur[RPB];
    __shared__ int wsum[FBLK / 64];
    __shared__ int carry;
    int bb = blockIdx.x;
    int t = threadIdx.x, lane = t & 63, wid = t >> 6;

    const int* binned = nullptr;
    const int* curp = nullptr;
    int* row_beg = nullptr;
    int* row_end = nullptr;
    float* rsq_in = nullptr;
    int* col = nullptr;
    float* rsq_out = nullptr;
    int b = 0, n = 0, cap = 0;
    bool dstSide;
    if (bb < NB_UI) {
        dstSide = true; b = bb; n = N_ALL; cap = CAP_UI;
        binned = ui_binned; curp = curs + 0 * MAX_NB;
        row_beg = ui_row_beg; row_end = ui_row_end;
        rsq_in = ui_rsq_in; col = ui_col;
    } else if (bb < 2 * NB_UI) {
        dstSide = false; b = bb - NB_UI; n = N_ALL; cap = CAP_UI;
        binned = ui_binned_src; curp = curs + 1 * MAX_NB;
        rsq_out = ui_rsq_out;
    } else if (bb < 2 * NB_UI + NB_UU) {
        dstSide = true; b = bb - 2 * NB_UI; n = N_USER; cap = CAP_UU;
        binned = uu_binned; curp = curs + 2 * MAX_NB;
        row_beg = uu_row_beg; row_end = uu_row_end;
        rsq_in = uu_rsq_in; col = uu_col;
    } else {
        dstSide = false; b = bb - 2 * NB_UI - NB_UU; n = N_USER; cap = CAP_UU;
        binned = uu_binned_src; curp = curs + 3 * MAX_NB;
        rsq_out = uu_rsq_out;
    }

    int row0 = b << RPB_SHIFT;
    int beg = b * cap;
    int end = curp[b];

    if (!dstSide) {
        for (int i = t; i < RPB; i += FBLK) deg[i] = 0;
        __syncthreads();
        for (int e = beg + t; e < end; e += FBLK)
            atomicAdd(&deg[binned[e] - row0], 1);
        __syncthreads();
        for (int i = t; i < RPB; i += FBLK)
            if (row0 + i < n)
                rsq_out[row0 + i] = 1.0f / sqrtf(fmaxf((float)deg[i], 1.0f));
        return;
    }

    int nrows = min(RPB, n - row0);
    for (int i = t; i < RPB; i += FBLK) deg[i] = 0;
    __syncthreads();

    for (int e = beg + t; e < end; e += FBLK)
        atomicAdd(&deg[binned[e] >> SRC_BITS], 1);

    // chunked exclusive scan of deg[0..RPB) -> cur (absolute, bucket-strided)
    if (t == 0) carry = 0;
    for (int c0 = 0; c0 < RPB; c0 += FBLK) {
        __syncthreads();
        int x = deg[c0 + t];
        int s = wave_incl_scan(x, lane);
        if (lane == 63) wsum[wid] = s;
        __syncthreads();
        int add = carry;
        for (int w = 0; w < wid; ++w) add += wsum[w];
        int excl = add + s - x;
        cur[c0 + t] = beg + excl;
        if (c0 + t < nrows) {
            row_beg[row0 + c0 + t] = beg + excl;
            row_end[row0 + c0 + t] = beg + excl + x;
            rsq_in[row0 + c0 + t] = 1.0f / sqrtf(fmaxf((float)x, 1.0f));
        }
        int total = 0;
        #pragma unroll
        for (int w = 0; w < FBLK / 64; ++w) total += wsum[w];
        __syncthreads();
        if (t == 0) carry = add + total;
    }
    __syncthreads();

    // col scatter (mutates cur)
    for (int e = beg + t; e < end; e += FBLK) {
        int p = binned[e];
        int pos = atomicAdd(&cur[p >> SRC_BITS], 1);
        col[pos] = p & SRC_MASK;
    }
}

// ---------------- plain GCN layer: gather -> emb_out only (no sum I/O) ----------------

__global__ void gcn_layer_plain_kernel(const int* __restrict__ row_beg,
                                       const int* __restrict__ row_end,
                                       const int* __restrict__ col,
                                       const bf16* __restrict__ emb_in,
                                       const float* __restrict__ rsq_in,
                                       const float* __restrict__ rsq_out,
                                       bf16* __restrict__ emb_out,
                                       int n) {
    int wave = blockIdx.x * (blockDim.x >> 6) + (threadIdx.x >> 6);
    int lane = threadIdx.x & 63;
    int q = lane & 7;
    int row = wave * 8 + (lane >> 3);
    bool act = row < n;
    int beg = 0, end = 0;
    if (act) { beg = row_beg[row]; end = row_end[row]; }
    float rin = act ? rsq_in[row] : 0.f;
    float ro  = act ? rsq_out[row] : 0.f;

    float acc[8];
    #pragma unroll
    for (int k = 0; k < 8; ++k) acc[k] = 0.f;

    const int4* __restrict__ embv = (const int4*)emb_in;

    int e = beg;
    for (; e + 4 <= end; e += 4) {
        int s0 = col[e];
        int s1 = col[e + 1];
        int s2 = col[e + 2];
        int s3 = col[e + 3];
        int4 w0 = embv[(size_t)s0 * 8 + q];
        int4 w1 = embv[(size_t)s1 * 8 + q];
        int4 w2 = embv[(size_t)s2 * 8 + q];
        int4 w3 = embv[(size_t)s3 * 8 + q];
        acc8(acc, w0);
        acc8(acc, w1);
        acc8(acc, w2);
        acc8(acc, w3);
    }
    for (; e < end; ++e) {
        int4 w0 = embv[(size_t)col[e] * 8 + q];
        acc8(acc, w0);
    }

    float vv[8];
    #pragma unroll
    for (int k = 0; k < 8; ++k) {
        float v = acc[k] * rin;
        vv[k] = (v > 0.f) ? v : 0.5f * v;   // LeakyReLU(0.5)
    }

    if (act) {
        size_t o = (size_t)row * D + (size_t)q * 8;
        union { i32x4 i4; bf16 h[8]; } pk;
        #pragma unroll
        for (int k = 0; k < 8; ++k) pk.h[k] = __float2bfloat16(vv[k] * ro);
        __builtin_nontemporal_store(pk.i4, (i32x4*)(emb_out + o));
    }
}

// ---------------- final GCN layer: own contribution + recomputed prior norms ----------------
// sum_out[row] = init[row] + n(prev1[row]) [+ n(prev2[row])] + v/||v||

__global__ void gcn_layer_final_kernel(const int* __restrict__ row_beg,
                                       const int* __restrict__ row_end,
                                       const int* __restrict__ col,
                                       const bf16* __restrict__ emb_in,
                                       const float* __restrict__ rsq_in,
                                       const float* __restrict__ initA,
                                       const float* __restrict__ initB,
                                       long splitElems,
                                       const bf16* __restrict__ prev1,
                                       const bf16* __restrict__ prev2,
                                       float* __restrict__ sum_out,
                                       int n) {
    int wave = blockIdx.x * (blockDim.x >> 6) + (threadIdx.x >> 6);
    int lane = threadIdx.x & 63;
    int q = lane & 7;
    int row = wave * 8 + (lane >> 3);
    bool act = row < n;
    int beg = 0, end = 0;
    if (act) { beg = row_beg[row]; end = row_end[row]; }
    float rin = act ? rsq_in[row] : 0.f;
    size_t o = (size_t)row * D + (size_t)q * 8;

    // hoisted: init base (nt, streamed once)
    f32x4 i0 = {0.f, 0.f, 0.f, 0.f}, i1 = {0.f, 0.f, 0.f, 0.f};
    if (act) {
        const float* bsrc = ((size_t)row * D < (size_t)splitElems)
                                ? (initA + o) : (initB + (o - splitElems));
        const f32x4* sp = (const f32x4*)bsrc;
        i0 = __builtin_nontemporal_load(sp);
        i1 = __builtin_nontemporal_load(sp + 1);
    }
    // hoisted: prior emb rows
    float p1f[8], p2f[8];
    #pragma unroll
    for (int k = 0; k < 8; ++k) { p1f[k] = 0.f; p2f[k] = 0.f; }
    if (act) {
        size_t idx2 = (size_t)row * 8 + q;
        i32x4 p1;
        if (prev1 == emb_in) p1 = *((const i32x4*)prev1 + idx2);   // gather table: keep cached
        else p1 = __builtin_nontemporal_load((const i32x4*)prev1 + idx2);
        unpack8(p1, p1f);
        if (prev2) {
            i32x4 p2 = *((const i32x4*)prev2 + idx2);
            unpack8(p2, p2f);
        }
    }

    float acc[8];
    #pragma unroll
    for (int k = 0; k < 8; ++k) acc[k] = 0.f;

    const int4* __restrict__ embv = (const int4*)emb_in;

    int e = beg;
    for (; e + 4 <= end; e += 4) {
        int s0 = col[e];
        int s1 = col[e + 1];
        int s2 = col[e + 2];
        int s3 = col[e + 3];
        int4 w0 = embv[(size_t)s0 * 8 + q];
        int4 w1 = embv[(size_t)s1 * 8 + q];
        int4 w2 = embv[(size_t)s2 * 8 + q];
        int4 w3 = embv[(size_t)s3 * 8 + q];
        acc8(acc, w0);
        acc8(acc, w1);
        acc8(acc, w2);
        acc8(acc, w3);
    }
    for (; e < end; ++e) {
        int4 w0 = embv[(size_t)col[e] * 8 + q];
        acc8(acc, w0);
    }

    float vv[8];
    #pragma unroll
    for (int k = 0; k < 8; ++k) {
        float v = acc[k] * rin;
        vv[k] = (v > 0.f) ? v : 0.5f * v;   // LeakyReLU(0.5)
    }
    float invO = groupnorm_inv(vv);
    float inv1 = groupnorm_inv(p1f);
    float inv2 = prev2 ? groupnorm_inv(p2f) : 0.f;

    if (act) {
        f32x4 o0, o1;
        o0.x = i0.x + p1f[0] * inv1 + p2f[0] * inv2 + vv[0] * invO;
        o0.y = i0.y + p1f[1] * inv1 + p2f[1] * inv2 + vv[1] * invO;
        o0.z = i0.z + p1f[2] * inv1 + p2f[2] * inv2 + vv[2] * invO;
        o0.w = i0.w + p1f[3] * inv1 + p2f[3] * inv2 + vv[3] * invO;
        o1.x = i1.x + p1f[4] * inv1 + p2f[4] * inv2 + vv[4] * invO;
        o1.y = i1.y + p1f[5] * inv1 + p2f[5] * inv2 + vv[5] * invO;
        o1.z = i1.z + p1f[6] * inv1 + p2f[6] * inv2 + vv[6] * invO;
        o1.w = i1.w + p1f[7] * inv1 + p2f[7] * inv2 + vv[7] * invO;
        f32x4* op = (f32x4*)(sum_out + o);
        __builtin_nontemporal_store(o0, op);
        __builtin_nontemporal_store(o1, op + 1);
    }
}

// ---------------- host side ----------------

extern "C" void kernel_launch(void* const* d_in, const int* in_sizes, int n_in,
                              void* d_out, int out_size, void* d_ws, size_t ws_size,
                              hipStream_t stream) {
    const float* user_emb = (const float*)d_in[0];
    const float* item_emb = (const float*)d_in[1];
    const int*   ui_src   = (const int*)d_in[2];
    const int*   ui_dst   = (const int*)d_in[3];
    const int*   uu_src   = (const int*)d_in[4];
    const int*   uu_dst   = (const int*)d_in[5];

    float* out    = (float*)d_out;
    float* ui_sum = out;                          // [N_ALL * D]
    float* uu_sum = out + (size_t)N_ALL * D;      // [N_USER * D]

    // ws layout (~135 MB total)
    char* wp = (char*)d_ws;
    bf16* embA = (bf16*)wp;        wp += (size_t)N_ALL * D * sizeof(bf16);      // 38.4 MB
    bf16* embB = (bf16*)wp;        wp += (size_t)N_ALL * D * sizeof(bf16);      // 38.4 MB
    int* ui_binned     = (int*)wp; wp += (size_t)NB_UI * CAP_UI * sizeof(int);  // 16.1 MB
    int* ui_binned_src = (int*)wp; wp += (size_t)NB_UI * CAP_UI * sizeof(int);  // 16.1 MB
    int* uu_binned     = (int*)wp; wp += (size_t)NB_UU * CAP_UU * sizeof(int);  // 8.0 MB
    int* uu_binned_src = (int*)wp; wp += (size_t)NB_UU * CAP_UU * sizeof(int);  // 8.0 MB
    int* uu_col        = (int*)wp; wp += (size_t)NB_UU * CAP_UU * sizeof(int);  // 8.0 MB
    int*   uu_row_beg = (int*)wp;   wp += (size_t)N_USER * sizeof(int);
    int*   uu_row_end = (int*)wp;   wp += (size_t)N_USER * sizeof(int);
    float* uu_rsq_out = (float*)wp; wp += (size_t)N_USER * sizeof(float);
    float* uu_rsq_in  = (float*)wp; wp += (size_t)N_USER * sizeof(float);
    int* curs = (int*)wp;           wp += 4 * (size_t)MAX_NB * sizeof(int);

    // UI CSR scratch in the uu_sum region of d_out (dead during UI phase; ~21 MB of 25.6)
    char* p = (char*)uu_sum;
    int*   ui_col     = (int*)p;   p += (size_t)NB_UI * CAP_UI * sizeof(int);   // 16.1 MB
    int*   ui_row_beg = (int*)p;   p += (size_t)N_ALL * sizeof(int);
    int*   ui_row_end = (int*)p;   p += (size_t)N_ALL * sizeof(int);
    float* ui_rsq_out = (float*)p; p += (size_t)N_ALL * sizeof(float);
    float* ui_rsq_in  = (float*)p; p += (size_t)N_ALL * sizeof(float);

    // ---------------- build (both graphs; no hist, fixed-capacity buckets) ----------------
    init_cursors_kernel<<<1, BLK, 0, stream>>>(curs);
    bin_scatter2_both_kernel<<<T_UI + T_UU, SBLK, 0, stream>>>(
        ui_src, ui_dst, uu_src, uu_dst, curs,
        ui_binned_src, ui_binned, uu_binned_src, uu_binned);
    bucket_finalize_both_kernel<<<2 * NB_UI + 2 * NB_UU, FBLK, 0, stream>>>(
        ui_binned, ui_binned_src, uu_binned, uu_binned_src, curs,
        ui_row_beg, ui_row_end, ui_rsq_in, ui_col, ui_rsq_out,
        uu_row_beg, uu_row_end, uu_rsq_in, uu_col, uu_rsq_out);

    const int ROWS_PER_BLK = (BLK / 64) * 8;  // 32

    // ---------------- user-item graph ----------------
    {
        size_t tot = (size_t)N_ALL * D;
        init_ui_kernel<<<cdiv((int)tot, BLK), BLK, 0, stream>>>(
            user_emb, item_emb, ui_rsq_out, embA);

        int grid = cdiv(N_ALL, ROWS_PER_BLK);
        // l0: A -> B (emb_1)
        gcn_layer_plain_kernel<<<grid, BLK, 0, stream>>>(
            ui_row_beg, ui_row_end, ui_col, embA, ui_rsq_in, ui_rsq_out, embB, N_ALL);
        // l1: B -> A (emb_2)
        gcn_layer_plain_kernel<<<grid, BLK, 0, stream>>>(
            ui_row_beg, ui_row_end, ui_col, embB, ui_rsq_in, ui_rsq_out, embA, N_ALL);
        // l2: gather A, combine init + n(emb_1=B) + n(emb_2=A) + own -> ui_sum
        gcn_layer_final_kernel<<<grid, BLK, 0, stream>>>(
            ui_row_beg, ui_row_end, ui_col, embA, ui_rsq_in,
            user_emb, item_emb, (long)N_USER * D,
            embB, embA, ui_sum, N_ALL);
    }

    // ---------------- user-user graph ----------------
    {
        size_t tot = (size_t)N_USER * D;
        init_uu_kernel<<<cdiv((int)tot, BLK), BLK, 0, stream>>>(
            user_emb, uu_rsq_out, embA);

        int grid = cdiv(N_USER, ROWS_PER_BLK);
        // l0: A -> B (emb_1)
        gcn_layer_plain_kernel<<<grid, BLK, 0, stream>>>(
            uu_row_beg, uu_row_end, uu_col, embA, uu_rsq_in, uu_rsq_out, embB, N_USER);
        // l1: gather B, combine init(ue) + n(emb_1=B) + own -> uu_sum
        gcn_layer_final_kernel<<<grid, BLK, 0, stream>>>(
            uu_row_beg, uu_row_end, uu_col, embB, uu_rsq_in,
            user_emb, nullptr, (long)N_USER * D,
            embB, nullptr, uu_sum, N_USER);
    }
}

// Round 18
// 451.613 us; speedup vs baseline: 1.2183x; 1.0322x over previous
//
#include <hip/hip_runtime.h>
#include <hip/hip_bf16.h>

constexpr int N_USER = 100000;
constexpr int N_ITEM = 200000;
constexpr int N_ALL  = N_USER + N_ITEM;
constexpr int E_UI   = 3200000;
constexpr int E_UU   = 1600000;
constexpr int D      = 64;
constexpr int BLK    = 256;

// bucketing: 2048 rows per bucket
constexpr int RPB_SHIFT = 11;
constexpr int RPB       = 1 << RPB_SHIFT;   // 2048
constexpr int MAX_NB    = 160;
constexpr int SRC_BITS  = 19;               // N_ALL < 2^19
constexpr int SRC_MASK  = (1 << SRC_BITS) - 1;

// fixed per-bucket capacity (mean + >35 sigma for uniform-random endpoints)
constexpr int NB_UI = (N_ALL  + RPB - 1) / RPB;  // 147
constexpr int NB_UU = (N_USER + RPB - 1) / RPB;  // 49
constexpr int CAP_UI = 27392;               // mean 21845, sigma ~147
constexpr int CAP_UU = 40960;               // mean 32768, sigma ~179

// bin_scatter tile geometry
constexpr int SBLK = 512;
constexpr int EPT  = 16;
constexpr int TILE = SBLK * EPT;            // 8192 edges per block

constexpr int FBLK = 1024;                  // finalize block (16 waves)

constexpr int T_UI  = (E_UI + TILE - 1) / TILE;  // 391
constexpr int T_UU  = (E_UU + TILE - 1) / TILE;  // 196

constexpr int ROWS_PER_BLK = (BLK / 64) * 8;               // 32
constexpr int GRID_UI = (N_ALL  + ROWS_PER_BLK - 1) / ROWS_PER_BLK;  // 9375
constexpr int GRID_UU = (N_USER + ROWS_PER_BLK - 1) / ROWS_PER_BLK;  // 3125

typedef __hip_bfloat16 bf16;
typedef float f32x4 __attribute__((ext_vector_type(4)));
typedef int   i32x4 __attribute__((ext_vector_type(4)));

// ---------------- small helpers ----------------

__device__ inline int wave_incl_scan(int x, int lane) {
    #pragma unroll
    for (int off = 1; off < 64; off <<= 1) {
        int y = __shfl_up(x, off, 64);
        if (lane >= off) x += y;
    }
    return x;
}

static inline int cdiv(int a, int b) { return (a + b - 1) / b; }

// accumulate 8 bf16 (packed in an int4) into 8 f32 accumulators
__device__ inline void acc8(float* acc, const int4 v) {
    acc[0] += __int_as_float(v.x << 16);
    acc[1] += __int_as_float(v.x & 0xffff0000);
    acc[2] += __int_as_float(v.y << 16);
    acc[3] += __int_as_float(v.y & 0xffff0000);
    acc[4] += __int_as_float(v.z << 16);
    acc[5] += __int_as_float(v.z & 0xffff0000);
    acc[6] += __int_as_float(v.w << 16);
    acc[7] += __int_as_float(v.w & 0xffff0000);
}

__device__ inline void unpack8(const i32x4 v, float* f) {
    f[0] = __int_as_float(v.x << 16);
    f[1] = __int_as_float(v.x & 0xffff0000);
    f[2] = __int_as_float(v.y << 16);
    f[3] = __int_as_float(v.y & 0xffff0000);
    f[4] = __int_as_float(v.z << 16);
    f[5] = __int_as_float(v.z & 0xffff0000);
    f[6] = __int_as_float(v.w << 16);
    f[7] = __int_as_float(v.w & 0xffff0000);
}

// L2-norm inverse across the 8 lanes of one row slot
__device__ inline float groupnorm_inv(const float* f) {
    float ss = 0.f;
    #pragma unroll
    for (int k = 0; k < 8; ++k) ss += f[k] * f[k];
    ss += __shfl_xor(ss, 1, 64);
    ss += __shfl_xor(ss, 2, 64);
    ss += __shfl_xor(ss, 4, 64);
    return 1.0f / fmaxf(sqrtf(ss), 1e-12f);
}

// ---------------- init kernels ----------------

__global__ void init_ui_kernel(const float* __restrict__ ue,
                               const float* __restrict__ ie,
                               const float* __restrict__ rsq_out,
                               bf16* __restrict__ emb_scaled) {
    size_t t = (size_t)blockIdx.x * blockDim.x + threadIdx.x;
    const size_t total = (size_t)N_ALL * D;
    if (t >= total) return;
    const size_t userN = (size_t)N_USER * D;
    float v = (t < userN) ? ue[t] : ie[t - userN];
    int row = (int)(t >> 6);
    emb_scaled[t] = __float2bfloat16(v * rsq_out[row]);
}

__global__ void init_uu_kernel(const float* __restrict__ ue,
                               const float* __restrict__ rsq_out,
                               bf16* __restrict__ emb_scaled) {
    size_t t = (size_t)blockIdx.x * blockDim.x + threadIdx.x;
    const size_t total = (size_t)N_USER * D;
    if (t >= total) return;
    float v = ue[t];
    int row = (int)(t >> 6);
    emb_scaled[t] = __float2bfloat16(v * rsq_out[row]);
}

// ---------------- cursor init: curX[b] = b * CAP ----------------
// layout: [UI_D | UI_S | UU_D | UU_S], each MAX_NB ints.

__global__ void init_cursors_kernel(int* __restrict__ curs) {
    int t = threadIdx.x;
    if (t < NB_UI) {
        curs[0 * MAX_NB + t] = t * CAP_UI;
        curs[1 * MAX_NB + t] = t * CAP_UI;
    }
    if (t < NB_UU) {
        curs[2 * MAX_NB + t] = t * CAP_UU;
        curs[3 * MAX_NB + t] = t * CAP_UU;
    }
}

// ---------------- merged bin scatter: both graphs, both sides, one edge pass ----------------
// dst record packed as (dstLocal << SRC_BITS) | src. Output bucket-strided at CAP.

__global__ __launch_bounds__(SBLK) void bin_scatter2_both_kernel(
    const int* __restrict__ ui_src, const int* __restrict__ ui_dst,
    const int* __restrict__ uu_src, const int* __restrict__ uu_dst,
    int* __restrict__ curs,
    int* __restrict__ ui_binned_src, int* __restrict__ ui_binned,
    int* __restrict__ uu_binned_src, int* __restrict__ uu_binned) {
    __shared__ int cS[MAX_NB];
    __shared__ int bS[MAX_NB];
    __shared__ int cD[MAX_NB];
    __shared__ int bD[MAX_NB];
    bool isUI = blockIdx.x < T_UI;
    const int* src = isUI ? ui_src : uu_src;
    const int* dst = isUI ? ui_dst : uu_dst;
    int E  = isUI ? E_UI : E_UU;
    int nb = isUI ? NB_UI : NB_UU;
    int* curD = curs + (isUI ? 0 : 2 * MAX_NB);
    int* curS = curD + MAX_NB;
    int* bsrc = isUI ? ui_binned_src : uu_binned_src;
    int* bpk  = isUI ? ui_binned : uu_binned;
    int ti = isUI ? blockIdx.x : blockIdx.x - T_UI;

    int t = threadIdx.x;
    for (int b = t; b < nb; b += SBLK) { cS[b] = 0; cD[b] = 0; }
    __syncthreads();
    int base_e = ti * TILE;
    int mys[EPT], myd[EPT], myrS[EPT], myrD[EPT];
    #pragma unroll
    for (int j = 0; j < EPT; ++j) {
        int e = base_e + j * SBLK + t;
        if (e < E) {
            int s = src[e];
            int d = dst[e];
            mys[j] = s;
            myd[j] = d;
            myrS[j] = atomicAdd(&cS[s >> RPB_SHIFT], 1);
            myrD[j] = atomicAdd(&cD[d >> RPB_SHIFT], 1);
        } else {
            myd[j] = -1;
        }
    }
    __syncthreads();
    for (int b = t; b < nb; b += SBLK) {
        if (cS[b] > 0) bS[b] = atomicAdd(&curS[b], cS[b]);
        if (cD[b] > 0) bD[b] = atomicAdd(&curD[b], cD[b]);
    }
    __syncthreads();
    #pragma unroll
    for (int j = 0; j < EPT; ++j) {
        if (myd[j] >= 0) {
            int s = mys[j], d = myd[j];
            bsrc[bS[s >> RPB_SHIFT] + myrS[j]] = s;
            bpk[bD[d >> RPB_SHIFT] + myrD[j]] = ((d & (RPB - 1)) << SRC_BITS) | s;
        }
    }
}

// ---------------- merged per-bucket finalize ----------------

__global__ __launch_bounds__(FBLK) void bucket_finalize_both_kernel(
    const int* __restrict__ ui_binned, const int* __restrict__ ui_binned_src,
    const int* __restrict__ uu_binned, const int* __restrict__ uu_binned_src,
    const int* __restrict__ curs,
    int* __restrict__ ui_row_beg, int* __restrict__ ui_row_end,
    float* __restrict__ ui_rsq_in,
    int* __restrict__ ui_col, float* __restrict__ ui_rsq_out,
    int* __restrict__ uu_row_beg, int* __restrict__ uu_row_end,
    float* __restrict__ uu_rsq_in,
    int* __restrict__ uu_col, float* __restrict__ uu_rsq_out) {
    __shared__ int deg[RPB];
    __shared__ int cur[RPB];
    __shared__ int wsum[FBLK / 64];
    __shared__ int carry;
    int bb = blockIdx.x;
    int t = threadIdx.x, lane = t & 63, wid = t >> 6;

    const int* binned = nullptr;
    const int* curp = nullptr;
    int* row_beg = nullptr;
    int* row_end = nullptr;
    float* rsq_in = nullptr;
    int* col = nullptr;
    float* rsq_out = nullptr;
    int b = 0, n = 0, cap = 0;
    bool dstSide;
    if (bb < NB_UI) {
        dstSide = true; b = bb; n = N_ALL; cap = CAP_UI;
        binned = ui_binned; curp = curs + 0 * MAX_NB;
        row_beg = ui_row_beg; row_end = ui_row_end;
        rsq_in = ui_rsq_in; col = ui_col;
    } else if (bb < 2 * NB_UI) {
        dstSide = false; b = bb - NB_UI; n = N_ALL; cap = CAP_UI;
        binned = ui_binned_src; curp = curs + 1 * MAX_NB;
        rsq_out = ui_rsq_out;
    } else if (bb < 2 * NB_UI + NB_UU) {
        dstSide = true; b = bb - 2 * NB_UI; n = N_USER; cap = CAP_UU;
        binned = uu_binned; curp = curs + 2 * MAX_NB;
        row_beg = uu_row_beg; row_end = uu_row_end;
        rsq_in = uu_rsq_in; col = uu_col;
    } else {
        dstSide = false; b = bb - 2 * NB_UI - NB_UU; n = N_USER; cap = CAP_UU;
        binned = uu_binned_src; curp = curs + 3 * MAX_NB;
        rsq_out = uu_rsq_out;
    }

    int row0 = b << RPB_SHIFT;
    int beg = b * cap;
    int end = curp[b];

    if (!dstSide) {
        for (int i = t; i < RPB; i += FBLK) deg[i] = 0;
        __syncthreads();
        for (int e = beg + t; e < end; e += FBLK)
            atomicAdd(&deg[binned[e] - row0], 1);
        __syncthreads();
        for (int i = t; i < RPB; i += FBLK)
            if (row0 + i < n)
                rsq_out[row0 + i] = 1.0f / sqrtf(fmaxf((float)deg[i], 1.0f));
        return;
    }

    int nrows = min(RPB, n - row0);
    for (int i = t; i < RPB; i += FBLK) deg[i] = 0;
    __syncthreads();

    for (int e = beg + t; e < end; e += FBLK)
        atomicAdd(&deg[binned[e] >> SRC_BITS], 1);

    // chunked exclusive scan of deg[0..RPB) -> cur (absolute, bucket-strided)
    if (t == 0) carry = 0;
    for (int c0 = 0; c0 < RPB; c0 += FBLK) {
        __syncthreads();
        int x = deg[c0 + t];
        int s = wave_incl_scan(x, lane);
        if (lane == 63) wsum[wid] = s;
        __syncthreads();
        int add = carry;
        for (int w = 0; w < wid; ++w) add += wsum[w];
        int excl = add + s - x;
        cur[c0 + t] = beg + excl;
        if (c0 + t < nrows) {
            row_beg[row0 + c0 + t] = beg + excl;
            row_end[row0 + c0 + t] = beg + excl + x;
            rsq_in[row0 + c0 + t] = 1.0f / sqrtf(fmaxf((float)x, 1.0f));
        }
        int total = 0;
        #pragma unroll
        for (int w = 0; w < FBLK / 64; ++w) total += wsum[w];
        __syncthreads();
        if (t == 0) carry = add + total;
    }
    __syncthreads();

    // col scatter (mutates cur)
    for (int e = beg + t; e < end; e += FBLK) {
        int p = binned[e];
        int pos = atomicAdd(&cur[p >> SRC_BITS], 1);
        col[pos] = p & SRC_MASK;
    }
}

// ---------------- plain layer pair: UI l0 || UU l0 (pointer-select, single body) ----------------

__global__ void layer_pair_plain_kernel(
    const int* __restrict__ ui_row_beg, const int* __restrict__ ui_row_end,
    const int* __restrict__ ui_col, const bf16* __restrict__ ui_in,
    const float* __restrict__ ui_rin, const float* __restrict__ ui_rout,
    bf16* __restrict__ ui_out,
    const int* __restrict__ uu_row_beg, const int* __restrict__ uu_row_end,
    const int* __restrict__ uu_col, const bf16* __restrict__ uu_in,
    const float* __restrict__ uu_rin, const float* __restrict__ uu_rout,
    bf16* __restrict__ uu_out) {
    bool isUI = blockIdx.x < GRID_UI;
    int bid = isUI ? (int)blockIdx.x : (int)blockIdx.x - GRID_UI;
    const int* row_beg = isUI ? ui_row_beg : uu_row_beg;
    const int* row_end = isUI ? ui_row_end : uu_row_end;
    const int* col     = isUI ? ui_col : uu_col;
    const bf16* emb_in = isUI ? ui_in : uu_in;
    const float* rsq_in  = isUI ? ui_rin : uu_rin;
    const float* rsq_out = isUI ? ui_rout : uu_rout;
    bf16* emb_out = isUI ? ui_out : uu_out;
    int n = isUI ? N_ALL : N_USER;

    int wave = bid * (BLK >> 6) + ((int)threadIdx.x >> 6);
    int lane = threadIdx.x & 63;
    int q = lane & 7;
    int row = wave * 8 + (lane >> 3);
    bool act = row < n;
    int beg = 0, end = 0;
    if (act) { beg = row_beg[row]; end = row_end[row]; }
    float rin = act ? rsq_in[row] : 0.f;
    float ro  = act ? rsq_out[row] : 0.f;

    float acc[8];
    #pragma unroll
    for (int k = 0; k < 8; ++k) acc[k] = 0.f;

    const int4* __restrict__ embv = (const int4*)emb_in;

    int e = beg;
    for (; e + 4 <= end; e += 4) {
        int s0 = col[e];
        int s1 = col[e + 1];
        int s2 = col[e + 2];
        int s3 = col[e + 3];
        int4 w0 = embv[(size_t)s0 * 8 + q];
        int4 w1 = embv[(size_t)s1 * 8 + q];
        int4 w2 = embv[(size_t)s2 * 8 + q];
        int4 w3 = embv[(size_t)s3 * 8 + q];
        acc8(acc, w0);
        acc8(acc, w1);
        acc8(acc, w2);
        acc8(acc, w3);
    }
    for (; e < end; ++e) {
        int4 w0 = embv[(size_t)col[e] * 8 + q];
        acc8(acc, w0);
    }

    float vv[8];
    #pragma unroll
    for (int k = 0; k < 8; ++k) {
        float v = acc[k] * rin;
        vv[k] = (v > 0.f) ? v : 0.5f * v;   // LeakyReLU(0.5)
    }

    if (act) {
        size_t o = (size_t)row * D + (size_t)q * 8;
        union { i32x4 i4; bf16 h[8]; } pk;
        #pragma unroll
        for (int k = 0; k < 8; ++k) pk.h[k] = __float2bfloat16(vv[k] * ro);
        __builtin_nontemporal_store(pk.i4, (i32x4*)(emb_out + o));
    }
}

// ---------------- standalone plain layer (UI l1) ----------------

__global__ void gcn_layer_plain_kernel(const int* __restrict__ row_beg,
                                       const int* __restrict__ row_end,
                                       const int* __restrict__ col,
                                       const bf16* __restrict__ emb_in,
                                       const float* __restrict__ rsq_in,
                                       const float* __restrict__ rsq_out,
                                       bf16* __restrict__ emb_out,
                                       int n) {
    int wave = blockIdx.x * (blockDim.x >> 6) + (threadIdx.x >> 6);
    int lane = threadIdx.x & 63;
    int q = lane & 7;
    int row = wave * 8 + (lane >> 3);
    bool act = row < n;
    int beg = 0, end = 0;
    if (act) { beg = row_beg[row]; end = row_end[row]; }
    float rin = act ? rsq_in[row] : 0.f;
    float ro  = act ? rsq_out[row] : 0.f;

    float acc[8];
    #pragma unroll
    for (int k = 0; k < 8; ++k) acc[k] = 0.f;

    const int4* __restrict__ embv = (const int4*)emb_in;

    int e = beg;
    for (; e + 4 <= end; e += 4) {
        int s0 = col[e];
        int s1 = col[e + 1];
        int s2 = col[e + 2];
        int s3 = col[e + 3];
        int4 w0 = embv[(size_t)s0 * 8 + q];
        int4 w1 = embv[(size_t)s1 * 8 + q];
        int4 w2 = embv[(size_t)s2 * 8 + q];
        int4 w3 = embv[(size_t)s3 * 8 + q];
        acc8(acc, w0);
        acc8(acc, w1);
        acc8(acc, w2);
        acc8(acc, w3);
    }
    for (; e < end; ++e) {
        int4 w0 = embv[(size_t)col[e] * 8 + q];
        acc8(acc, w0);
    }

    float vv[8];
    #pragma unroll
    for (int k = 0; k < 8; ++k) {
        float v = acc[k] * rin;
        vv[k] = (v > 0.f) ? v : 0.5f * v;   // LeakyReLU(0.5)
    }

    if (act) {
        size_t o = (size_t)row * D + (size_t)q * 8;
        union { i32x4 i4; bf16 h[8]; } pk;
        #pragma unroll
        for (int k = 0; k < 8; ++k) pk.h[k] = __float2bfloat16(vv[k] * ro);
        __builtin_nontemporal_store(pk.i4, (i32x4*)(emb_out + o));
    }
}

// ---------------- final layer pair: UI final || UU final (pointer-select, single body) ----------------
// sum_out[row] = init[row] + n(prev1[row]) [+ n(prev2[row])] + v/||v||

__global__ void layer_pair_final_kernel(
    const int* __restrict__ ui_row_beg, const int* __restrict__ ui_row_end,
    const int* __restrict__ ui_col, const bf16* __restrict__ ui_in,
    const float* __restrict__ ui_rin,
    const float* __restrict__ ue, const float* __restrict__ ie,
    const bf16* __restrict__ ui_prev1, const bf16* __restrict__ ui_prev2,
    float* __restrict__ ui_sum,
    const int* __restrict__ uu_row_beg, const int* __restrict__ uu_row_end,
    const int* __restrict__ uu_col, const bf16* __restrict__ uu_in,
    const float* __restrict__ uu_rin,
    float* __restrict__ uu_sum) {
    bool isUI = blockIdx.x < GRID_UI;
    int bid = isUI ? (int)blockIdx.x : (int)blockIdx.x - GRID_UI;
    const int* row_beg = isUI ? ui_row_beg : uu_row_beg;
    const int* row_end = isUI ? ui_row_end : uu_row_end;
    const int* col     = isUI ? ui_col : uu_col;
    const bf16* emb_in = isUI ? ui_in : uu_in;
    const float* rsq_in = isUI ? ui_rin : uu_rin;
    const float* initA = ue;
    const float* initB = isUI ? ie : nullptr;
    const bf16* prev1  = isUI ? ui_prev1 : uu_in;
    const bf16* prev2  = isUI ? ui_prev2 : nullptr;
    float* sum_out     = isUI ? ui_sum : uu_sum;
    int n = isUI ? N_ALL : N_USER;
    const long splitElems = (long)N_USER * D;

    int wave = bid * (BLK >> 6) + ((int)threadIdx.x >> 6);
    int lane = threadIdx.x & 63;
    int q = lane & 7;
    int row = wave * 8 + (lane >> 3);
    bool act = row < n;
    int beg = 0, end = 0;
    if (act) { beg = row_beg[row]; end = row_end[row]; }
    float rin = act ? rsq_in[row] : 0.f;
    size_t o = (size_t)row * D + (size_t)q * 8;

    // hoisted: init base (nt, streamed once)
    f32x4 i0 = {0.f, 0.f, 0.f, 0.f}, i1 = {0.f, 0.f, 0.f, 0.f};
    if (act) {
        const float* bsrc = ((size_t)row * D < (size_t)splitElems)
                                ? (initA + o) : (initB + (o - splitElems));
        const f32x4* sp = (const f32x4*)bsrc;
        i0 = __builtin_nontemporal_load(sp);
        i1 = __builtin_nontemporal_load(sp + 1);
    }
    // hoisted: prior emb rows
    float p1f[8], p2f[8];
    #pragma unroll
    for (int k = 0; k < 8; ++k) { p1f[k] = 0.f; p2f[k] = 0.f; }
    if (act) {
        size_t idx2 = (size_t)row * 8 + q;
        i32x4 p1;
        if (prev1 == emb_in) p1 = *((const i32x4*)prev1 + idx2);   // gather table: keep cached
        else p1 = __builtin_nontemporal_load((const i32x4*)prev1 + idx2);
        unpack8(p1, p1f);
        if (prev2) {
            i32x4 p2 = *((const i32x4*)prev2 + idx2);
            unpack8(p2, p2f);
        }
    }

    float acc[8];
    #pragma unroll
    for (int k = 0; k < 8; ++k) acc[k] = 0.f;

    const int4* __restrict__ embv = (const int4*)emb_in;

    int e = beg;
    for (; e + 4 <= end; e += 4) {
        int s0 = col[e];
        int s1 = col[e + 1];
        int s2 = col[e + 2];
        int s3 = col[e + 3];
        int4 w0 = embv[(size_t)s0 * 8 + q];
        int4 w1 = embv[(size_t)s1 * 8 + q];
        int4 w2 = embv[(size_t)s2 * 8 + q];
        int4 w3 = embv[(size_t)s3 * 8 + q];
        acc8(acc, w0);
        acc8(acc, w1);
        acc8(acc, w2);
        acc8(acc, w3);
    }
    for (; e < end; ++e) {
        int4 w0 = embv[(size_t)col[e] * 8 + q];
        acc8(acc, w0);
    }

    float vv[8];
    #pragma unroll
    for (int k = 0; k < 8; ++k) {
        float v = acc[k] * rin;
        vv[k] = (v > 0.f) ? v : 0.5f * v;   // LeakyReLU(0.5)
    }
    float invO = groupnorm_inv(vv);
    float inv1 = groupnorm_inv(p1f);
    float inv2 = prev2 ? groupnorm_inv(p2f) : 0.f;

    if (act) {
        f32x4 o0, o1;
        o0.x = i0.x + p1f[0] * inv1 + p2f[0] * inv2 + vv[0] * invO;
        o0.y = i0.y + p1f[1] * inv1 + p2f[1] * inv2 + vv[1] * invO;
        o0.z = i0.z + p1f[2] * inv1 + p2f[2] * inv2 + vv[2] * invO;
        o0.w = i0.w + p1f[3] * inv1 + p2f[3] * inv2 + vv[3] * invO;
        o1.x = i1.x + p1f[4] * inv1 + p2f[4] * inv2 + vv[4] * invO;
        o1.y = i1.y + p1f[5] * inv1 + p2f[5] * inv2 + vv[5] * invO;
        o1.z = i1.z + p1f[6] * inv1 + p2f[6] * inv2 + vv[6] * invO;
        o1.w = i1.w + p1f[7] * inv1 + p2f[7] * inv2 + vv[7] * invO;
        f32x4* op = (f32x4*)(sum_out + o);
        __builtin_nontemporal_store(o0, op);
        __builtin_nontemporal_store(o1, op + 1);
    }
}

// ---------------- host side ----------------

extern "C" void kernel_launch(void* const* d_in, const int* in_sizes, int n_in,
                              void* d_out, int out_size, void* d_ws, size_t ws_size,
                              hipStream_t stream) {
    const float* user_emb = (const float*)d_in[0];
    const float* item_emb = (const float*)d_in[1];
    const int*   ui_src   = (const int*)d_in[2];
    const int*   ui_dst   = (const int*)d_in[3];
    const int*   uu_src   = (const int*)d_in[4];
    const int*   uu_dst   = (const int*)d_in[5];

    float* out    = (float*)d_out;
    float* ui_sum = out;                          // [N_ALL * D]
    float* uu_sum = out + (size_t)N_ALL * D;      // [N_USER * D]

    // ws layout (~155.6 MB; round 0 proved >= 156.0 MB available)
    char* wp = (char*)d_ws;
    bf16* embA = (bf16*)wp;        wp += (size_t)N_ALL * D * sizeof(bf16);      // 38.4 MB
    bf16* embB = (bf16*)wp;        wp += (size_t)N_ALL * D * sizeof(bf16);      // 38.4 MB
    int* ui_binned     = (int*)wp; wp += (size_t)NB_UI * CAP_UI * sizeof(int);  // 16.1 MB
    int* ui_binned_src = (int*)wp; wp += (size_t)NB_UI * CAP_UI * sizeof(int);  // 16.1 MB
    int* uu_binned     = (int*)wp; wp += (size_t)NB_UU * CAP_UU * sizeof(int);  // 8.0 MB
    int* uu_binned_src = (int*)wp; wp += (size_t)NB_UU * CAP_UU * sizeof(int);  // 8.0 MB
    int* ui_col        = (int*)wp; wp += (size_t)NB_UI * CAP_UI * sizeof(int);  // 16.1 MB
    int* uu_col        = (int*)wp; wp += (size_t)NB_UU * CAP_UU * sizeof(int);  // 8.0 MB
    int*   ui_row_beg = (int*)wp;   wp += (size_t)N_ALL * sizeof(int);
    int*   ui_row_end = (int*)wp;   wp += (size_t)N_ALL * sizeof(int);
    float* ui_rsq_out = (float*)wp; wp += (size_t)N_ALL * sizeof(float);
    float* ui_rsq_in  = (float*)wp; wp += (size_t)N_ALL * sizeof(float);
    int*   uu_row_beg = (int*)wp;   wp += (size_t)N_USER * sizeof(int);
    int*   uu_row_end = (int*)wp;   wp += (size_t)N_USER * sizeof(int);
    float* uu_rsq_out = (float*)wp; wp += (size_t)N_USER * sizeof(float);
    float* uu_rsq_in  = (float*)wp; wp += (size_t)N_USER * sizeof(float);
    int* curs = (int*)wp;           wp += 4 * (size_t)MAX_NB * sizeof(int);

    // UU emb buffers alias UI binned regions (dead after finalize).
    // N_USER*D*2B = 12.8 MB <= NB_UI*CAP_UI*4B = 16.1 MB.
    bf16* uu_emb0 = (bf16*)ui_binned;
    bf16* uu_emb1 = (bf16*)ui_binned_src;

    // ---------------- build (both graphs; fixed-capacity buckets) ----------------
    init_cursors_kernel<<<1, BLK, 0, stream>>>(curs);
    bin_scatter2_both_kernel<<<T_UI + T_UU, SBLK, 0, stream>>>(
        ui_src, ui_dst, uu_src, uu_dst, curs,
        ui_binned_src, ui_binned, uu_binned_src, uu_binned);
    bucket_finalize_both_kernel<<<2 * NB_UI + 2 * NB_UU, FBLK, 0, stream>>>(
        ui_binned, ui_binned_src, uu_binned, uu_binned_src, curs,
        ui_row_beg, ui_row_end, ui_rsq_in, ui_col, ui_rsq_out,
        uu_row_beg, uu_row_end, uu_rsq_in, uu_col, uu_rsq_out);

    // ---------------- init (binned regions dead after finalize) ----------------
    {
        size_t tot = (size_t)N_ALL * D;
        init_ui_kernel<<<cdiv((int)tot, BLK), BLK, 0, stream>>>(
            user_emb, item_emb, ui_rsq_out, embA);
        size_t tot2 = (size_t)N_USER * D;
        init_uu_kernel<<<cdiv((int)tot2, BLK), BLK, 0, stream>>>(
            user_emb, uu_rsq_out, uu_emb0);
    }

    // ---------------- layers ----------------
    // L1: UI l0 (embA -> embB) || UU l0 (uu_emb0 -> uu_emb1)
    layer_pair_plain_kernel<<<GRID_UI + GRID_UU, BLK, 0, stream>>>(
        ui_row_beg, ui_row_end, ui_col, embA, ui_rsq_in, ui_rsq_out, embB,
        uu_row_beg, uu_row_end, uu_col, uu_emb0, uu_rsq_in, uu_rsq_out, uu_emb1);

    // L2: UI l1 (embB -> embA)
    gcn_layer_plain_kernel<<<GRID_UI, BLK, 0, stream>>>(
        ui_row_beg, ui_row_end, ui_col, embB, ui_rsq_in, ui_rsq_out, embA, N_ALL);

    // L3: UI final (gather embA; init ue/ie; prev embB/embA -> ui_sum)
    //  || UU final (gather uu_emb1; init ue; prev1 uu_emb1 -> uu_sum)
    layer_pair_final_kernel<<<GRID_UI + GRID_UU, BLK, 0, stream>>>(
        ui_row_beg, ui_row_end, ui_col, embA, ui_rsq_in,
        user_emb, item_emb, embB, embA, ui_sum,
        uu_row_beg, uu_row_end, uu_col, uu_emb1, uu_rsq_in, uu_sum);
}

// Round 20
// 451.398 us; speedup vs baseline: 1.2189x; 1.0005x over previous
//
#include <hip/hip_runtime.h>
#include <hip/hip_bf16.h>

constexpr int N_USER = 100000;
constexpr int N_ITEM = 200000;
constexpr int N_ALL  = N_USER + N_ITEM;
constexpr int E_UI   = 3200000;
constexpr int E_UU   = 1600000;
constexpr int D      = 64;
constexpr int BLK    = 256;

// bucketing: 2048 rows per bucket
constexpr int RPB_SHIFT = 11;
constexpr int RPB       = 1 << RPB_SHIFT;   // 2048
constexpr int MAX_NB    = 160;
constexpr int SRC_BITS  = 19;               // N_ALL < 2^19
constexpr int SRC_MASK  = (1 << SRC_BITS) - 1;

// fixed per-bucket capacity (mean + >35 sigma for uniform-random endpoints)
constexpr int NB_UI = (N_ALL  + RPB - 1) / RPB;  // 147
constexpr int NB_UU = (N_USER + RPB - 1) / RPB;  // 49
constexpr int CAP_UI = 27392;               // mean 21845, sigma ~147
constexpr int CAP_UU = 40960;               // mean 32768, sigma ~179

// bin_scatter tile geometry
constexpr int SBLK = 512;
constexpr int EPT  = 16;
constexpr int TILE = SBLK * EPT;            // 8192 edges per block

constexpr int FBLK = 1024;                  // finalize block (16 waves)

constexpr int T_UI  = (E_UI + TILE - 1) / TILE;  // 391
constexpr int T_UU  = (E_UU + TILE - 1) / TILE;  // 196

constexpr int ROWS_PER_BLK = (BLK / 64) * 8;               // 32
constexpr int GRID_UI = (N_ALL  + ROWS_PER_BLK - 1) / ROWS_PER_BLK;  // 9375
constexpr int GRID_UU = (N_USER + ROWS_PER_BLK - 1) / ROWS_PER_BLK;  // 3125

typedef __hip_bfloat16 bf16;
typedef float f32x4 __attribute__((ext_vector_type(4)));
typedef int   i32x4 __attribute__((ext_vector_type(4)));

// ---------------- small helpers ----------------

__device__ inline int wave_incl_scan(int x, int lane) {
    #pragma unroll
    for (int off = 1; off < 64; off <<= 1) {
        int y = __shfl_up(x, off, 64);
        if (lane >= off) x += y;
    }
    return x;
}

static inline int cdiv(int a, int b) { return (a + b - 1) / b; }

// accumulate 8 bf16 (packed in an int4) into 8 f32 accumulators
__device__ inline void acc8(float* acc, const int4 v) {
    acc[0] += __int_as_float(v.x << 16);
    acc[1] += __int_as_float(v.x & 0xffff0000);
    acc[2] += __int_as_float(v.y << 16);
    acc[3] += __int_as_float(v.y & 0xffff0000);
    acc[4] += __int_as_float(v.z << 16);
    acc[5] += __int_as_float(v.z & 0xffff0000);
    acc[6] += __int_as_float(v.w << 16);
    acc[7] += __int_as_float(v.w & 0xffff0000);
}

__device__ inline void unpack8(const i32x4 v, float* f) {
    f[0] = __int_as_float(v.x << 16);
    f[1] = __int_as_float(v.x & 0xffff0000);
    f[2] = __int_as_float(v.y << 16);
    f[3] = __int_as_float(v.y & 0xffff0000);
    f[4] = __int_as_float(v.z << 16);
    f[5] = __int_as_float(v.z & 0xffff0000);
    f[6] = __int_as_float(v.w << 16);
    f[7] = __int_as_float(v.w & 0xffff0000);
}

// L2-norm inverse across the 8 lanes of one row slot
__device__ inline float groupnorm_inv(const float* f) {
    float ss = 0.f;
    #pragma unroll
    for (int k = 0; k < 8; ++k) ss += f[k] * f[k];
    ss += __shfl_xor(ss, 1, 64);
    ss += __shfl_xor(ss, 2, 64);
    ss += __shfl_xor(ss, 4, 64);
    return 1.0f / fmaxf(sqrtf(ss), 1e-12f);
}

// ---------------- merged init: UI emb (embA) + UU emb (uu_emb0), one dispatch ----------------

__global__ void init_both_kernel(const float* __restrict__ ue,
                                 const float* __restrict__ ie,
                                 const float* __restrict__ ui_rsq_out,
                                 const float* __restrict__ uu_rsq_out,
                                 bf16* __restrict__ embA,
                                 bf16* __restrict__ uu_emb0) {
    size_t t = (size_t)blockIdx.x * blockDim.x + threadIdx.x;
    const size_t uiTot = (size_t)N_ALL * D;
    const size_t userN = (size_t)N_USER * D;
    if (t < uiTot) {
        float v = (t < userN) ? ue[t] : ie[t - userN];
        int row = (int)(t >> 6);
        embA[t] = __float2bfloat16(v * ui_rsq_out[row]);
    } else {
        size_t u = t - uiTot;
        if (u < userN) {
            float v = ue[u];
            int row = (int)(u >> 6);
            uu_emb0[u] = __float2bfloat16(v * uu_rsq_out[row]);
        }
    }
}

// ---------------- cursor init: curX[b] = b * CAP ----------------
// layout: [UI_D | UI_S | UU_D | UU_S], each MAX_NB ints.

__global__ void init_cursors_kernel(int* __restrict__ curs) {
    int t = threadIdx.x;
    if (t < NB_UI) {
        curs[0 * MAX_NB + t] = t * CAP_UI;
        curs[1 * MAX_NB + t] = t * CAP_UI;
    }
    if (t < NB_UU) {
        curs[2 * MAX_NB + t] = t * CAP_UU;
        curs[3 * MAX_NB + t] = t * CAP_UU;
    }
}

// ---------------- merged bin scatter: both graphs, both sides, one edge pass ----------------
// dst record packed as (dstLocal << SRC_BITS) | src. Output bucket-strided at CAP.

__global__ __launch_bounds__(SBLK) void bin_scatter2_both_kernel(
    const int* __restrict__ ui_src, const int* __restrict__ ui_dst,
    const int* __restrict__ uu_src, const int* __restrict__ uu_dst,
    int* __restrict__ curs,
    int* __restrict__ ui_binned_src, int* __restrict__ ui_binned,
    int* __restrict__ uu_binned_src, int* __restrict__ uu_binned) {
    __shared__ int cS[MAX_NB];
    __shared__ int bS[MAX_NB];
    __shared__ int cD[MAX_NB];
    __shared__ int bD[MAX_NB];
    bool isUI = blockIdx.x < T_UI;
    const int* src = isUI ? ui_src : uu_src;
    const int* dst = isUI ? ui_dst : uu_dst;
    int E  = isUI ? E_UI : E_UU;
    int nb = isUI ? NB_UI : NB_UU;
    int* curD = curs + (isUI ? 0 : 2 * MAX_NB);
    int* curS = curD + MAX_NB;
    int* bsrc = isUI ? ui_binned_src : uu_binned_src;
    int* bpk  = isUI ? ui_binned : uu_binned;
    int ti = isUI ? blockIdx.x : blockIdx.x - T_UI;

    int t = threadIdx.x;
    for (int b = t; b < nb; b += SBLK) { cS[b] = 0; cD[b] = 0; }
    __syncthreads();
    int base_e = ti * TILE;
    int mys[EPT], myd[EPT], myrS[EPT], myrD[EPT];
    #pragma unroll
    for (int j = 0; j < EPT; ++j) {
        int e = base_e + j * SBLK + t;
        if (e < E) {
            int s = src[e];
            int d = dst[e];
            mys[j] = s;
            myd[j] = d;
            myrS[j] = atomicAdd(&cS[s >> RPB_SHIFT], 1);
            myrD[j] = atomicAdd(&cD[d >> RPB_SHIFT], 1);
        } else {
            myd[j] = -1;
        }
    }
    __syncthreads();
    for (int b = t; b < nb; b += SBLK) {
        if (cS[b] > 0) bS[b] = atomicAdd(&curS[b], cS[b]);
        if (cD[b] > 0) bD[b] = atomicAdd(&curD[b], cD[b]);
    }
    __syncthreads();
    #pragma unroll
    for (int j = 0; j < EPT; ++j) {
        if (myd[j] >= 0) {
            int s = mys[j], d = myd[j];
            bsrc[bS[s >> RPB_SHIFT] + myrS[j]] = s;
            bpk[bD[d >> RPB_SHIFT] + myrD[j]] = ((d & (RPB - 1)) << SRC_BITS) | s;
        }
    }
}

// ---------------- merged per-bucket finalize ----------------

__global__ __launch_bounds__(FBLK) void bucket_finalize_both_kernel(
    const int* __restrict__ ui_binned, const int* __restrict__ ui_binned_src,
    const int* __restrict__ uu_binned, const int* __restrict__ uu_binned_src,
    const int* __restrict__ curs,
    int* __restrict__ ui_row_beg, int* __restrict__ ui_row_end,
    float* __restrict__ ui_rsq_in,
    int* __restrict__ ui_col, float* __restrict__ ui_rsq_out,
    int* __restrict__ uu_row_beg, int* __restrict__ uu_row_end,
    float* __restrict__ uu_rsq_in,
    int* __restrict__ uu_col, float* __restrict__ uu_rsq_out) {
    __shared__ int deg[RPB];
    __shared__ int cur[RPB];
    __shared__ int wsum[FBLK / 64];
    __shared__ int carry;
    int bb = blockIdx.x;
    int t = threadIdx.x, lane = t & 63, wid = t >> 6;

    const int* binned = nullptr;
    const int* curp = nullptr;
    int* row_beg = nullptr;
    int* row_end = nullptr;
    float* rsq_in = nullptr;
    int* col = nullptr;
    float* rsq_out = nullptr;
    int b = 0, n = 0, cap = 0;
    bool dstSide;
    if (bb < NB_UI) {
        dstSide = true; b = bb; n = N_ALL; cap = CAP_UI;
        binned = ui_binned; curp = curs + 0 * MAX_NB;
        row_beg = ui_row_beg; row_end = ui_row_end;
        rsq_in = ui_rsq_in; col = ui_col;
    } else if (bb < 2 * NB_UI) {
        dstSide = false; b = bb - NB_UI; n = N_ALL; cap = CAP_UI;
        binned = ui_binned_src; curp = curs + 1 * MAX_NB;
        rsq_out = ui_rsq_out;
    } else if (bb < 2 * NB_UI + NB_UU) {
        dstSide = true; b = bb - 2 * NB_UI; n = N_USER; cap = CAP_UU;
        binned = uu_binned; curp = curs + 2 * MAX_NB;
        row_beg = uu_row_beg; row_end = uu_row_end;
        rsq_in = uu_rsq_in; col = uu_col;
    } else {
        dstSide = false; b = bb - 2 * NB_UI - NB_UU; n = N_USER; cap = CAP_UU;
        binned = uu_binned_src; curp = curs + 3 * MAX_NB;
        rsq_out = uu_rsq_out;
    }

    int row0 = b << RPB_SHIFT;
    int beg = b * cap;
    int end = curp[b];

    if (!dstSide) {
        for (int i = t; i < RPB; i += FBLK) deg[i] = 0;
        __syncthreads();
        for (int e = beg + t; e < end; e += FBLK)
            atomicAdd(&deg[binned[e] - row0], 1);
        __syncthreads();
        for (int i = t; i < RPB; i += FBLK)
            if (row0 + i < n)
                rsq_out[row0 + i] = 1.0f / sqrtf(fmaxf((float)deg[i], 1.0f));
        return;
    }

    int nrows = min(RPB, n - row0);
    for (int i = t; i < RPB; i += FBLK) deg[i] = 0;
    __syncthreads();

    for (int e = beg + t; e < end; e += FBLK)
        atomicAdd(&deg[binned[e] >> SRC_BITS], 1);

    // chunked exclusive scan of deg[0..RPB) -> cur (absolute, bucket-strided)
    if (t == 0) carry = 0;
    for (int c0 = 0; c0 < RPB; c0 += FBLK) {
        __syncthreads();
        int x = deg[c0 + t];
        int s = wave_incl_scan(x, lane);
        if (lane == 63) wsum[wid] = s;
        __syncthreads();
        int add = carry;
        for (int w = 0; w < wid; ++w) add += wsum[w];
        int excl = add + s - x;
        cur[c0 + t] = beg + excl;
        if (c0 + t < nrows) {
            row_beg[row0 + c0 + t] = beg + excl;
            row_end[row0 + c0 + t] = beg + excl + x;
            rsq_in[row0 + c0 + t] = 1.0f / sqrtf(fmaxf((float)x, 1.0f));
        }
        int total = 0;
        #pragma unroll
        for (int w = 0; w < FBLK / 64; ++w) total += wsum[w];
        __syncthreads();
        if (t == 0) carry = add + total;
    }
    __syncthreads();

    // col scatter (mutates cur)
    for (int e = beg + t; e < end; e += FBLK) {
        int p = binned[e];
        int pos = atomicAdd(&cur[p >> SRC_BITS], 1);
        col[pos] = p & SRC_MASK;
    }
}

// ---------------- plain layer pair: UI l0 || UU l0 (pointer-select, single body) ----------------

__global__ void layer_pair_plain_kernel(
    const int* __restrict__ ui_row_beg, const int* __restrict__ ui_row_end,
    const int* __restrict__ ui_col, const bf16* __restrict__ ui_in,
    const float* __restrict__ ui_rin, const float* __restrict__ ui_rout,
    bf16* __restrict__ ui_out,
    const int* __restrict__ uu_row_beg, const int* __restrict__ uu_row_end,
    const int* __restrict__ uu_col, const bf16* __restrict__ uu_in,
    const float* __restrict__ uu_rin, const float* __restrict__ uu_rout,
    bf16* __restrict__ uu_out) {
    bool isUI = blockIdx.x < GRID_UI;
    int bid = isUI ? (int)blockIdx.x : (int)blockIdx.x - GRID_UI;
    const int* row_beg = isUI ? ui_row_beg : uu_row_beg;
    const int* row_end = isUI ? ui_row_end : uu_row_end;
    const int* col     = isUI ? ui_col : uu_col;
    const bf16* emb_in = isUI ? ui_in : uu_in;
    const float* rsq_in  = isUI ? ui_rin : uu_rin;
    const float* rsq_out = isUI ? ui_rout : uu_rout;
    bf16* emb_out = isUI ? ui_out : uu_out;
    int n = isUI ? N_ALL : N_USER;

    int wave = bid * (BLK >> 6) + ((int)threadIdx.x >> 6);
    int lane = threadIdx.x & 63;
    int q = lane & 7;
    int row = wave * 8 + (lane >> 3);
    bool act = row < n;
    int beg = 0, end = 0;
    if (act) { beg = row_beg[row]; end = row_end[row]; }
    float rin = act ? rsq_in[row] : 0.f;
    float ro  = act ? rsq_out[row] : 0.f;

    float acc[8];
    #pragma unroll
    for (int k = 0; k < 8; ++k) acc[k] = 0.f;

    const int4* __restrict__ embv = (const int4*)emb_in;

    int e = beg;
    for (; e + 4 <= end; e += 4) {
        int s0 = col[e];
        int s1 = col[e + 1];
        int s2 = col[e + 2];
        int s3 = col[e + 3];
        int4 w0 = embv[(size_t)s0 * 8 + q];
        int4 w1 = embv[(size_t)s1 * 8 + q];
        int4 w2 = embv[(size_t)s2 * 8 + q];
        int4 w3 = embv[(size_t)s3 * 8 + q];
        acc8(acc, w0);
        acc8(acc, w1);
        acc8(acc, w2);
        acc8(acc, w3);
    }
    for (; e < end; ++e) {
        int4 w0 = embv[(size_t)col[e] * 8 + q];
        acc8(acc, w0);
    }

    float vv[8];
    #pragma unroll
    for (int k = 0; k < 8; ++k) {
        float v = acc[k] * rin;
        vv[k] = (v > 0.f) ? v : 0.5f * v;   // LeakyReLU(0.5)
    }

    if (act) {
        size_t o = (size_t)row * D + (size_t)q * 8;
        union { i32x4 i4; bf16 h[8]; } pk;
        #pragma unroll
        for (int k = 0; k < 8; ++k) pk.h[k] = __float2bfloat16(vv[k] * ro);
        __builtin_nontemporal_store(pk.i4, (i32x4*)(emb_out + o));
    }
}

// ---------------- standalone plain layer (UI l1) ----------------

__global__ void gcn_layer_plain_kernel(const int* __restrict__ row_beg,
                                       const int* __restrict__ row_end,
                                       const int* __restrict__ col,
                                       const bf16* __restrict__ emb_in,
                                       const float* __restrict__ rsq_in,
                                       const float* __restrict__ rsq_out,
                                       bf16* __restrict__ emb_out,
                                       int n) {
    int wave = blockIdx.x * (blockDim.x >> 6) + (threadIdx.x >> 6);
    int lane = threadIdx.x & 63;
    int q = lane & 7;
    int row = wave * 8 + (lane >> 3);
    bool act = row < n;
    int beg = 0, end = 0;
    if (act) { beg = row_beg[row]; end = row_end[row]; }
    float rin = act ? rsq_in[row] : 0.f;
    float ro  = act ? rsq_out[row] : 0.f;

    float acc[8];
    #pragma unroll
    for (int k = 0; k < 8; ++k) acc[k] = 0.f;

    const int4* __restrict__ embv = (const int4*)emb_in;

    int e = beg;
    for (; e + 4 <= end; e += 4) {
        int s0 = col[e];
        int s1 = col[e + 1];
        int s2 = col[e + 2];
        int s3 = col[e + 3];
        int4 w0 = embv[(size_t)s0 * 8 + q];
        int4 w1 = embv[(size_t)s1 * 8 + q];
        int4 w2 = embv[(size_t)s2 * 8 + q];
        int4 w3 = embv[(size_t)s3 * 8 + q];
        acc8(acc, w0);
        acc8(acc, w1);
        acc8(acc, w2);
        acc8(acc, w3);
    }
    for (; e < end; ++e) {
        int4 w0 = embv[(size_t)col[e] * 8 + q];
        acc8(acc, w0);
    }

    float vv[8];
    #pragma unroll
    for (int k = 0; k < 8; ++k) {
        float v = acc[k] * rin;
        vv[k] = (v > 0.f) ? v : 0.5f * v;   // LeakyReLU(0.5)
    }

    if (act) {
        size_t o = (size_t)row * D + (size_t)q * 8;
        union { i32x4 i4; bf16 h[8]; } pk;
        #pragma unroll
        for (int k = 0; k < 8; ++k) pk.h[k] = __float2bfloat16(vv[k] * ro);
        __builtin_nontemporal_store(pk.i4, (i32x4*)(emb_out + o));
    }
}

// ---------------- final layer pair: UI final || UU final (pointer-select, single body) ----------------
// sum_out[row] = init[row] + n(prev1[row]) [+ n(prev2[row])] + v/||v||

__global__ void layer_pair_final_kernel(
    const int* __restrict__ ui_row_beg, const int* __restrict__ ui_row_end,
    const int* __restrict__ ui_col, const bf16* __restrict__ ui_in,
    const float* __restrict__ ui_rin,
    const float* __restrict__ ue, const float* __restrict__ ie,
    const bf16* __restrict__ ui_prev1, const bf16* __restrict__ ui_prev2,
    float* __restrict__ ui_sum,
    const int* __restrict__ uu_row_beg, const int* __restrict__ uu_row_end,
    const int* __restrict__ uu_col, const bf16* __restrict__ uu_in,
    const float* __restrict__ uu_rin,
    float* __restrict__ uu_sum) {
    bool isUI = blockIdx.x < GRID_UI;
    int bid = isUI ? (int)blockIdx.x : (int)blockIdx.x - GRID_UI;
    const int* row_beg = isUI ? ui_row_beg : uu_row_beg;
    const int* row_end = isUI ? ui_row_end : uu_row_end;
    const int* col     = isUI ? ui_col : uu_col;
    const bf16* emb_in = isUI ? ui_in : uu_in;
    const float* rsq_in = isUI ? ui_rin : uu_rin;
    const float* initA = ue;
    const float* initB = isUI ? ie : nullptr;
    const bf16* prev1  = isUI ? ui_prev1 : uu_in;
    const bf16* prev2  = isUI ? ui_prev2 : nullptr;
    float* sum_out     = isUI ? ui_sum : uu_sum;
    int n = isUI ? N_ALL : N_USER;
    const long splitElems = (long)N_USER * D;

    int wave = bid * (BLK >> 6) + ((int)threadIdx.x >> 6);
    int lane = threadIdx.x & 63;
    int q = lane & 7;
    int row = wave * 8 + (lane >> 3);
    bool act = row < n;
    int beg = 0, end = 0;
    if (act) { beg = row_beg[row]; end = row_end[row]; }
    float rin = act ? rsq_in[row] : 0.f;
    size_t o = (size_t)row * D + (size_t)q * 8;

    // hoisted: init base (nt, streamed once)
    f32x4 i0 = {0.f, 0.f, 0.f, 0.f}, i1 = {0.f, 0.f, 0.f, 0.f};
    if (act) {
        const float* bsrc = ((size_t)row * D < (size_t)splitElems)
                                ? (initA + o) : (initB + (o - splitElems));
        const f32x4* sp = (const f32x4*)bsrc;
        i0 = __builtin_nontemporal_load(sp);
        i1 = __builtin_nontemporal_load(sp + 1);
    }
    // hoisted: prior emb rows
    float p1f[8], p2f[8];
    #pragma unroll
    for (int k = 0; k < 8; ++k) { p1f[k] = 0.f; p2f[k] = 0.f; }
    if (act) {
        size_t idx2 = (size_t)row * 8 + q;
        i32x4 p1;
        if (prev1 == emb_in) p1 = *((const i32x4*)prev1 + idx2);   // gather table: keep cached
        else p1 = __builtin_nontemporal_load((const i32x4*)prev1 + idx2);
        unpack8(p1, p1f);
        if (prev2) {
            i32x4 p2 = *((const i32x4*)prev2 + idx2);
            unpack8(p2, p2f);
        }
    }

    float acc[8];
    #pragma unroll
    for (int k = 0; k < 8; ++k) acc[k] = 0.f;

    const int4* __restrict__ embv = (const int4*)emb_in;

    int e = beg;
    for (; e + 4 <= end; e += 4) {
        int s0 = col[e];
        int s1 = col[e + 1];
        int s2 = col[e + 2];
        int s3 = col[e + 3];
        int4 w0 = embv[(size_t)s0 * 8 + q];
        int4 w1 = embv[(size_t)s1 * 8 + q];
        int4 w2 = embv[(size_t)s2 * 8 + q];
        int4 w3 = embv[(size_t)s3 * 8 + q];
        acc8(acc, w0);
        acc8(acc, w1);
        acc8(acc, w2);
        acc8(acc, w3);
    }
    for (; e < end; ++e) {
        int4 w0 = embv[(size_t)col[e] * 8 + q];
        acc8(acc, w0);
    }

    float vv[8];
    #pragma unroll
    for (int k = 0; k < 8; ++k) {
        float v = acc[k] * rin;
        vv[k] = (v > 0.f) ? v : 0.5f * v;   // LeakyReLU(0.5)
    }
    float invO = groupnorm_inv(vv);
    float inv1 = groupnorm_inv(p1f);
    float inv2 = prev2 ? groupnorm_inv(p2f) : 0.f;

    if (act) {
        f32x4 o0, o1;
        o0.x = i0.x + p1f[0] * inv1 + p2f[0] * inv2 + vv[0] * invO;
        o0.y = i0.y + p1f[1] * inv1 + p2f[1] * inv2 + vv[1] * invO;
        o0.z = i0.z + p1f[2] * inv1 + p2f[2] * inv2 + vv[2] * invO;
        o0.w = i0.w + p1f[3] * inv1 + p2f[3] * inv2 + vv[3] * invO;
        o1.x = i1.x + p1f[4] * inv1 + p2f[4] * inv2 + vv[4] * invO;
        o1.y = i1.y + p1f[5] * inv1 + p2f[5] * inv2 + vv[5] * invO;
        o1.z = i1.z + p1f[6] * inv1 + p2f[6] * inv2 + vv[6] * invO;
        o1.w = i1.w + p1f[7] * inv1 + p2f[7] * inv2 + vv[7] * invO;
        f32x4* op = (f32x4*)(sum_out + o);
        __builtin_nontemporal_store(o0, op);
        __builtin_nontemporal_store(o1, op + 1);
    }
}

// ---------------- host side ----------------

extern "C" void kernel_launch(void* const* d_in, const int* in_sizes, int n_in,
                              void* d_out, int out_size, void* d_ws, size_t ws_size,
                              hipStream_t stream) {
    const float* user_emb = (const float*)d_in[0];
    const float* item_emb = (const float*)d_in[1];
    const int*   ui_src   = (const int*)d_in[2];
    const int*   ui_dst   = (const int*)d_in[3];
    const int*   uu_src   = (const int*)d_in[4];
    const int*   uu_dst   = (const int*)d_in[5];

    float* out    = (float*)d_out;
    float* ui_sum = out;                          // [N_ALL * D]
    float* uu_sum = out + (size_t)N_ALL * D;      // [N_USER * D]

    // ws layout (~155.6 MB; round 0 proved >= 156.0 MB available)
    char* wp = (char*)d_ws;
    bf16* embA = (bf16*)wp;        wp += (size_t)N_ALL * D * sizeof(bf16);      // 38.4 MB
    bf16* embB = (bf16*)wp;        wp += (size_t)N_ALL * D * sizeof(bf16);      // 38.4 MB
    int* ui_binned     = (int*)wp; wp += (size_t)NB_UI * CAP_UI * sizeof(int);  // 16.1 MB
    int* ui_binned_src = (int*)wp; wp += (size_t)NB_UI * CAP_UI * sizeof(int);  // 16.1 MB
    int* uu_binned     = (int*)wp; wp += (size_t)NB_UU * CAP_UU * sizeof(int);  // 8.0 MB
    int* uu_binned_src = (int*)wp; wp += (size_t)NB_UU * CAP_UU * sizeof(int);  // 8.0 MB
    int* ui_col        = (int*)wp; wp += (size_t)NB_UI * CAP_UI * sizeof(int);  // 16.1 MB
    int* uu_col        = (int*)wp; wp += (size_t)NB_UU * CAP_UU * sizeof(int);  // 8.0 MB
    int*   ui_row_beg = (int*)wp;   wp += (size_t)N_ALL * sizeof(int);
    int*   ui_row_end = (int*)wp;   wp += (size_t)N_ALL * sizeof(int);
    float* ui_rsq_out = (float*)wp; wp += (size_t)N_ALL * sizeof(float);
    float* ui_rsq_in  = (float*)wp; wp += (size_t)N_ALL * sizeof(float);
    int*   uu_row_beg = (int*)wp;   wp += (size_t)N_USER * sizeof(int);
    int*   uu_row_end = (int*)wp;   wp += (size_t)N_USER * sizeof(int);
    float* uu_rsq_out = (float*)wp; wp += (size_t)N_USER * sizeof(float);
    float* uu_rsq_in  = (float*)wp; wp += (size_t)N_USER * sizeof(float);
    int* curs = (int*)wp;           wp += 4 * (size_t)MAX_NB * sizeof(int);

    // UU emb buffers alias UI binned regions (dead after finalize).
    // N_USER*D*2B = 12.8 MB <= NB_UI*CAP_UI*4B = 16.1 MB.
    bf16* uu_emb0 = (bf16*)ui_binned;
    bf16* uu_emb1 = (bf16*)ui_binned_src;

    // ---------------- build (both graphs; fixed-capacity buckets) ----------------
    init_cursors_kernel<<<1, BLK, 0, stream>>>(curs);
    bin_scatter2_both_kernel<<<T_UI + T_UU, SBLK, 0, stream>>>(
        ui_src, ui_dst, uu_src, uu_dst, curs,
        ui_binned_src, ui_binned, uu_binned_src, uu_binned);
    bucket_finalize_both_kernel<<<2 * NB_UI + 2 * NB_UU, FBLK, 0, stream>>>(
        ui_binned, ui_binned_src, uu_binned, uu_binned_src, curs,
        ui_row_beg, ui_row_end, ui_rsq_in, ui_col, ui_rsq_out,
        uu_row_beg, uu_row_end, uu_rsq_in, uu_col, uu_rsq_out);

    // ---------------- init (binned regions dead after finalize; one dispatch) ----------------
    size_t initTot = (size_t)N_ALL * D + (size_t)N_USER * D;
    init_both_kernel<<<cdiv((int)initTot, BLK), BLK, 0, stream>>>(
        user_emb, item_emb, ui_rsq_out, uu_rsq_out, embA, uu_emb0);

    // ---------------- layers ----------------
    // L1: UI l0 (embA -> embB) || UU l0 (uu_emb0 -> uu_emb1)
    layer_pair_plain_kernel<<<GRID_UI + GRID_UU, BLK, 0, stream>>>(
        ui_row_beg, ui_row_end, ui_col, embA, ui_rsq_in, ui_rsq_out, embB,
        uu_row_beg, uu_row_end, uu_col, uu_emb0, uu_rsq_in, uu_rsq_out, uu_emb1);

    // L2: UI l1 (embB -> embA)
    gcn_layer_plain_kernel<<<GRID_UI, BLK, 0, stream>>>(
        ui_row_beg, ui_row_end, ui_col, embB, ui_rsq_in, ui_rsq_out, embA, N_ALL);

    // L3: UI final (gather embA; init ue/ie; prev embB/embA -> ui_sum)
    //  || UU final (gather uu_emb1; init ue; prev1 uu_emb1 -> uu_sum)
    layer_pair_final_kernel<<<GRID_UI + GRID_UU, BLK, 0, stream>>>(
        ui_row_beg, ui_row_end, ui_col, embA, ui_rsq_in,
        user_emb, item_emb, embB, embA, ui_sum,
        uu_row_beg, uu_row_end, uu_col, uu_emb1, uu_rsq_in, uu_sum);
}